// Round 3
// baseline (379.197 us; speedup 1.0000x reference)
//
#include <hip/hip_runtime.h>
#include <hip/hip_bf16.h>

// GatedDeltaNet: B=2, T=1024, D=2048, HK=8, HV=16, DK=DV=128, KW=4
#define B_ 2
#define T_ 1024
#define D_ 2048
#define HK_ 8
#define HV_ 16
#define DK_ 128
#define DV_ 128
#define KEY_DIM_ 1024
#define VALUE_DIM_ 2048
#define CONV_DIM_ 4096
#define BT_ 2048   // B*T
#define NCH_ 16    // chunks per sequence (T/64)
#define CL_ 64     // chunk length

typedef __attribute__((ext_vector_type(8))) short short8;
typedef __attribute__((ext_vector_type(4))) float f32x4;

__device__ __forceinline__ short f2bf(float x) {
  __hip_bfloat16 h = __float2bfloat16(x);
  return *reinterpret_cast<short*>(&h);
}
__device__ __forceinline__ float bf2f(short u) {
  unsigned int x = ((unsigned int)(unsigned short)u) << 16;
  return __int_as_float(x);
}

#define GLOAD_LDS16(g, l)                                             \
  __builtin_amdgcn_global_load_lds(                                   \
      (const __attribute__((address_space(1))) void*)(g),             \
      (__attribute__((address_space(3))) void*)(l), 16, 0, 0)

// ---------------- transpose + cast: W[R,C] f32 -> WT[C,R] bf16 ----------------
__global__ void transpose_cast(const float* __restrict__ W, short* __restrict__ WT, int R, int C) {
  __shared__ float tile[32][33];
  int tx = threadIdx.x, ty = threadIdx.y;
  int x = blockIdx.x * 32 + tx;
#pragma unroll
  for (int j = 0; j < 4; ++j) {
    int r = blockIdx.y * 32 + ty + j * 8;
    tile[ty + j * 8][tx] = W[(long)r * C + x];
  }
  __syncthreads();
  int ro = blockIdx.y * 32 + tx;
#pragma unroll
  for (int j = 0; j < 4; ++j) {
    int co = blockIdx.x * 32 + ty + j * 8;
    WT[(long)co * R + ro] = f2bf(tile[tx][ty + j * 8]);
  }
}

// ---------------- W_b|W_a -> Wba32[k][32] (k-major interleave) ----------------
__global__ void interleave_ba(const float* __restrict__ Wb, const float* __restrict__ Wa,
                              float* __restrict__ Wba32) {
  int i = blockIdx.x * 256 + threadIdx.x;   // D*32
  int c = i & 31, k = i >> 5;
  Wba32[i] = (c < 16) ? Wb[k * 16 + c] : Wa[k * 16 + (c - 16)];
}

// ================= 256x256 8-phase GEMM (T2+T3+T4+T5), split output =========
// BM=BN=256, BK=64, 8 waves (512 thr), LDS 128 KiB (2 bufs x (A 256x64 | B 256x64)).
// XOR-swizzle (shorts): col ^= (row&7)<<3, applied on pre-swizzled global source
// (LDS dest stays linear for global_load_lds) and on ds_read addresses.
// Stage ring: 16 KB units, 1 per phase; vmcnt(6) only at phases 4 and 8.
__global__ __launch_bounds__(512) void gemm256_split(const short* __restrict__ A,
                                                     const short* __restrict__ Bt,
                                                     float* __restrict__ C0,
                                                     float* __restrict__ C1,
                                                     int N0, int N1, int K) {
  __shared__ short lds[65536];   // 128 KB
  const int tid = threadIdx.x;
  const int lane = tid & 63, wid = tid >> 6;
  const int quad = lane >> 4, l16 = lane & 15;
  const int wm = (wid >> 2) * 128, wn = (wid & 3) * 64;
  const int m0 = blockIdx.y * 256, n0 = blockIdx.x * 256;

  const int r8 = tid >> 3, t8 = (tid & 7) * 8;
  const int csw = t8 ^ ((r8 & 7) << 3);              // staging: swizzled global col
  const int rB = (r8 & 31) + ((r8 >> 5) << 6);       // B-unit row pattern
  const int cswr = (quad ^ (l16 & 7)) << 3;          // reader xor-col (kk=0)
  const int NT = K >> 6, NIT = NT >> 1;

  f32x4 acc[8][4] = {};
  short8 a[4][2], bl[2][2], bh[2][2];

#define SGA(p, kt, rb)                                                        \
  GLOAD_LDS16(A + (long)(m0 + (rb) + r8) * K + (kt) * 64 + csw,               \
              lds + (p) * 32768 + ((rb) + r8) * 64 + t8)
#define SGB(p, kt, rb)                                                        \
  GLOAD_LDS16(Bt + (long)(n0 + (rb) + rB) * K + (kt) * 64 + csw,              \
              lds + (p) * 32768 + 16384 + ((rb) + rB) * 64 + t8)
#define UA0(p, kt) do { SGA(p, kt, 0);  SGA(p, kt, 128); } while (0)
#define UA2(p, kt) do { SGA(p, kt, 64); SGA(p, kt, 192); } while (0)
#define UB1(p, kt) do { SGB(p, kt, 0);  SGB(p, kt, 128); } while (0)
#define UB3(p, kt) do { SGB(p, kt, 32); SGB(p, kt, 160); } while (0)
#define RDA(p, r, kk) (*(const short8*)(lds + (p) * 32768 + (r) * 64 + (cswr ^ ((kk) << 5))))
#define RDB(p, r, kk) (*(const short8*)(lds + (p) * 32768 + 16384 + (r) * 64 + (cswr ^ ((kk) << 5))))
#define MFMA_(d, x, y) d = __builtin_amdgcn_mfma_f32_16x16x32_bf16(x, y, d, 0, 0, 0)
#define BAR_() do { __builtin_amdgcn_s_barrier(); __builtin_amdgcn_sched_barrier(0); } while (0)
#define PRIO_ON_() __builtin_amdgcn_s_setprio(1)
#define PRIO_OFF_() do { __builtin_amdgcn_s_setprio(0); __builtin_amdgcn_sched_barrier(0); } while (0)

  // prologue: tile0 fully, tile1 u0/u1/u2  (14 loads outstanding -> wait 8 oldest)
  UA0(0, 0); UB1(0, 0); UA2(0, 0); UB3(0, 0);
  UA0(1, 1); UB1(1, 1); UA2(1, 1);
  asm volatile("s_waitcnt vmcnt(6)" ::: "memory");
  BAR_();

#pragma unroll 1
  for (int i = 0; i < NIT; ++i) {
    const int tb = 2 * i + 1, tc = 2 * i + 2, td = 2 * i + 3;
    const bool more = (i + 1 < NIT);

    // ---- ph1: buf0, m-lo x n-lo ----
#pragma unroll
    for (int mi = 0; mi < 4; ++mi) {
      a[mi][0] = RDA(0, wm + mi * 16 + l16, 0);
      a[mi][1] = RDA(0, wm + mi * 16 + l16, 1);
    }
#pragma unroll
    for (int ni = 0; ni < 2; ++ni) {
      bl[ni][0] = RDB(0, wn + ni * 16 + l16, 0);
      bl[ni][1] = RDB(0, wn + ni * 16 + l16, 1);
    }
    UB3(1, tb);
    BAR_();
    PRIO_ON_();
#pragma unroll
    for (int mi = 0; mi < 4; ++mi)
#pragma unroll
      for (int ni = 0; ni < 2; ++ni) {
        MFMA_(acc[mi][ni], a[mi][0], bl[ni][0]);
        MFMA_(acc[mi][ni], a[mi][1], bl[ni][1]);
      }
    PRIO_OFF_();
    __builtin_amdgcn_s_barrier();

    // ---- ph2: buf0, m-lo x n-hi ----
    __builtin_amdgcn_sched_barrier(0);
#pragma unroll
    for (int ni = 0; ni < 2; ++ni) {
      bh[ni][0] = RDB(0, wn + 32 + ni * 16 + l16, 0);
      bh[ni][1] = RDB(0, wn + 32 + ni * 16 + l16, 1);
    }
    if (more) UA0(0, tc);
    BAR_();
    PRIO_ON_();
#pragma unroll
    for (int mi = 0; mi < 4; ++mi)
#pragma unroll
      for (int ni = 0; ni < 2; ++ni) {
        MFMA_(acc[mi][2 + ni], a[mi][0], bh[ni][0]);
        MFMA_(acc[mi][2 + ni], a[mi][1], bh[ni][1]);
      }
    PRIO_OFF_();
    __builtin_amdgcn_s_barrier();

    // ---- ph3: buf0, m-hi x n-hi ----
    __builtin_amdgcn_sched_barrier(0);
#pragma unroll
    for (int mi = 0; mi < 4; ++mi) {
      a[mi][0] = RDA(0, wm + 64 + mi * 16 + l16, 0);
      a[mi][1] = RDA(0, wm + 64 + mi * 16 + l16, 1);
    }
    if (more) UB1(0, tc);
    BAR_();
    PRIO_ON_();
#pragma unroll
    for (int mi = 0; mi < 4; ++mi)
#pragma unroll
      for (int ni = 0; ni < 2; ++ni) {
        MFMA_(acc[4 + mi][2 + ni], a[mi][0], bh[ni][0]);
        MFMA_(acc[4 + mi][2 + ni], a[mi][1], bh[ni][1]);
      }
    PRIO_OFF_();
    __builtin_amdgcn_s_barrier();

    // ---- ph4: buf0, m-hi x n-lo (regs only) ----
    __builtin_amdgcn_sched_barrier(0);
    if (more) UA2(0, tc);
    BAR_();
    PRIO_ON_();
#pragma unroll
    for (int mi = 0; mi < 4; ++mi)
#pragma unroll
      for (int ni = 0; ni < 2; ++ni) {
        MFMA_(acc[4 + mi][ni], a[mi][0], bl[ni][0]);
        MFMA_(acc[4 + mi][ni], a[mi][1], bl[ni][1]);
      }
    PRIO_OFF_();
    if (more) { asm volatile("s_waitcnt vmcnt(6)" ::: "memory"); }
    else      { asm volatile("s_waitcnt vmcnt(0)" ::: "memory"); }
    __builtin_amdgcn_s_barrier();

    // ---- ph5: buf1, m-lo x n-lo ----
    __builtin_amdgcn_sched_barrier(0);
#pragma unroll
    for (int mi = 0; mi < 4; ++mi) {
      a[mi][0] = RDA(1, wm + mi * 16 + l16, 0);
      a[mi][1] = RDA(1, wm + mi * 16 + l16, 1);
    }
#pragma unroll
    for (int ni = 0; ni < 2; ++ni) {
      bl[ni][0] = RDB(1, wn + ni * 16 + l16, 0);
      bl[ni][1] = RDB(1, wn + ni * 16 + l16, 1);
    }
    if (more) UB3(0, tc);
    BAR_();
    PRIO_ON_();
#pragma unroll
    for (int mi = 0; mi < 4; ++mi)
#pragma unroll
      for (int ni = 0; ni < 2; ++ni) {
        MFMA_(acc[mi][ni], a[mi][0], bl[ni][0]);
        MFMA_(acc[mi][ni], a[mi][1], bl[ni][1]);
      }
    PRIO_OFF_();
    __builtin_amdgcn_s_barrier();

    // ---- ph6: buf1, m-lo x n-hi ----
    __builtin_amdgcn_sched_barrier(0);
#pragma unroll
    for (int ni = 0; ni < 2; ++ni) {
      bh[ni][0] = RDB(1, wn + 32 + ni * 16 + l16, 0);
      bh[ni][1] = RDB(1, wn + 32 + ni * 16 + l16, 1);
    }
    if (more) UA0(1, td);
    BAR_();
    PRIO_ON_();
#pragma unroll
    for (int mi = 0; mi < 4; ++mi)
#pragma unroll
      for (int ni = 0; ni < 2; ++ni) {
        MFMA_(acc[mi][2 + ni], a[mi][0], bh[ni][0]);
        MFMA_(acc[mi][2 + ni], a[mi][1], bh[ni][1]);
      }
    PRIO_OFF_();
    __builtin_amdgcn_s_barrier();

    // ---- ph7: buf1, m-hi x n-hi ----
    __builtin_amdgcn_sched_barrier(0);
#pragma unroll
    for (int mi = 0; mi < 4; ++mi) {
      a[mi][0] = RDA(1, wm + 64 + mi * 16 + l16, 0);
      a[mi][1] = RDA(1, wm + 64 + mi * 16 + l16, 1);
    }
    if (more) UB1(1, td);
    BAR_();
    PRIO_ON_();
#pragma unroll
    for (int mi = 0; mi < 4; ++mi)
#pragma unroll
      for (int ni = 0; ni < 2; ++ni) {
        MFMA_(acc[4 + mi][2 + ni], a[mi][0], bh[ni][0]);
        MFMA_(acc[4 + mi][2 + ni], a[mi][1], bh[ni][1]);
      }
    PRIO_OFF_();
    __builtin_amdgcn_s_barrier();

    // ---- ph8: buf1, m-hi x n-lo (regs only) ----
    __builtin_amdgcn_sched_barrier(0);
    if (more) UA2(1, td);
    BAR_();
    PRIO_ON_();
#pragma unroll
    for (int mi = 0; mi < 4; ++mi)
#pragma unroll
      for (int ni = 0; ni < 2; ++ni) {
        MFMA_(acc[4 + mi][ni], a[mi][0], bl[ni][0]);
        MFMA_(acc[4 + mi][ni], a[mi][1], bl[ni][1]);
      }
    PRIO_OFF_();
    if (more) { asm volatile("s_waitcnt vmcnt(6)" ::: "memory"); }
    else      { asm volatile("s_waitcnt vmcnt(0)" ::: "memory"); }
    __builtin_amdgcn_s_barrier();
    __builtin_amdgcn_sched_barrier(0);
  }

  float* Cw; int ldc, cb;
  if (n0 < N0) { Cw = C0; ldc = N0; cb = n0; }
  else         { Cw = C1; ldc = N1; cb = n0 - N0; }
#pragma unroll
  for (int mi = 0; mi < 8; ++mi)
#pragma unroll
    for (int ni = 0; ni < 4; ++ni)
#pragma unroll
      for (int r = 0; r < 4; ++r) {
        int row = m0 + wm + mi * 16 + quad * 4 + r;
        int col = cb + wn + ni * 16 + l16;
        Cw[(long)row * ldc + col] = acc[mi][ni][r];
      }
#undef SGA
#undef SGB
#undef UA0
#undef UA2
#undef UB1
#undef UB3
#undef RDA
#undef RDB
#undef MFMA_
#undef BAR_
#undef PRIO_ON_
#undef PRIO_OFF_
}

// ---------------- bf16 MFMA GEMM, split-K=2, dbuf + counted vmcnt ------------
__global__ __launch_bounds__(256) void gemm128_ks(const short* __restrict__ A,
                                                  const short* __restrict__ Bt,
                                                  float* __restrict__ Cp,
                                                  int M, int N, int K) {
  __shared__ short As[2][128 * 32];
  __shared__ short Bs[2][128 * 32];
  int m0 = blockIdx.y * 128, n0 = blockIdx.x * 128;
  int kh = K >> 1;
  int kbeg = blockIdx.z * kh;
  int tid = threadIdx.x;
  int wave = tid >> 6, lane = tid & 63;
  int wm = (wave >> 1) * 64, wn = (wave & 1) * 64;
  int quad = lane >> 4, l16 = lane & 15;
  f32x4 acc[4][4] = {};

  int ar = tid >> 2;
  int ac = (tid & 3) * 8;
  const short* Ag0 = A + (long)(m0 + ar) * K + ac + kbeg;
  const short* Ag1 = A + (long)(m0 + 64 + ar) * K + ac + kbeg;
  const short* Bg0 = Bt + (long)(n0 + ar) * K + ac + kbeg;
  const short* Bg1 = Bt + (long)(n0 + 64 + ar) * K + ac + kbeg;
  int NT = kh >> 5;

#define STAGE_(t, c)                                  \
  do {                                                \
    GLOAD_LDS16(Ag0 + (t) * 32, As[c] + tid * 8);     \
    GLOAD_LDS16(Ag1 + (t) * 32, As[c] + 64 * 32 + tid * 8); \
    GLOAD_LDS16(Bg0 + (t) * 32, Bs[c] + tid * 8);     \
    GLOAD_LDS16(Bg1 + (t) * 32, Bs[c] + 64 * 32 + tid * 8); \
  } while (0)

  STAGE_(0, 0);
  STAGE_(1, 1);

  for (int t = 0; t < NT; ++t) {
    int c = t & 1;
    if (t + 1 < NT) {
      asm volatile("s_waitcnt vmcnt(4)" ::: "memory");
    } else {
      asm volatile("s_waitcnt vmcnt(0)" ::: "memory");
    }
    __builtin_amdgcn_s_barrier();
    __builtin_amdgcn_sched_barrier(0);

    short8 af[4], bf_[4];
#pragma unroll
    for (int i = 0; i < 4; ++i) af[i] = *(const short8*)(As[c] + (wm + i * 16 + l16) * 32 + quad * 8);
#pragma unroll
    for (int j = 0; j < 4; ++j) bf_[j] = *(const short8*)(Bs[c] + (wn + j * 16 + l16) * 32 + quad * 8);
#pragma unroll
    for (int i = 0; i < 4; ++i)
#pragma unroll
      for (int j = 0; j < 4; ++j)
        acc[i][j] = __builtin_amdgcn_mfma_f32_16x16x32_bf16(af[i], bf_[j], acc[i][j], 0, 0, 0);

    __builtin_amdgcn_sched_barrier(0);
    __builtin_amdgcn_s_barrier();
    if (t + 2 < NT) STAGE_(t + 2, c);
  }

  float* Cz = Cp + (long)blockIdx.z * M * N;
#pragma unroll
  for (int i = 0; i < 4; ++i)
#pragma unroll
    for (int j = 0; j < 4; ++j)
#pragma unroll
      for (int r = 0; r < 4; ++r) {
        int row = m0 + wm + i * 16 + quad * 4 + r;
        int colx = n0 + wn + j * 16 + l16;
        Cz[(long)row * N + colx] = acc[i][j][r];
      }
#undef STAGE_
}

// ---------------- sum two split-K partials ----------------
__global__ void add2(const float* __restrict__ p0, const float* __restrict__ p1,
                     float* __restrict__ out, int n4) {
  int i = blockIdx.x * 256 + threadIdx.x;
  if (i < n4) {
    float4 a = ((const float4*)p0)[i];
    float4 b = ((const float4*)p1)[i];
    float4 o;
    o.x = a.x + b.x; o.y = a.y + b.y; o.z = a.z + b.z; o.w = a.w + b.w;
    ((float4*)out)[i] = o;
  }
}

// ---------------- beta / g projections + fused hidden bf16 cast --------------
__global__ __launch_bounds__(256) void small_proj(const float* __restrict__ hidden,
                                                  const float* __restrict__ Wba32,
                                                  const float* __restrict__ dt_bias,
                                                  const float* __restrict__ A_log,
                                                  float* __restrict__ betaT,
                                                  float* __restrict__ gT,
                                                  short* __restrict__ hbf) {
  __shared__ float red[2][32][33];
  int r0 = blockIdx.x * 2;
  int tid = threadIdx.x;
  int cg = tid & 7, s = tid >> 3;
  const f32x4* wp = (const f32x4*)Wba32 + (long)s * 64 * 8 + cg;
  const f32x4* h0 = (const f32x4*)(hidden + (long)r0 * D_ + s * 64);
  const f32x4* h1 = (const f32x4*)(hidden + (long)(r0 + 1) * D_ + s * 64);
  f32x4 a0 = {0.f, 0.f, 0.f, 0.f}, a1 = {0.f, 0.f, 0.f, 0.f};
#pragma unroll
  for (int ii = 0; ii < 16; ++ii) {
    f32x4 ha = h0[ii], hb = h1[ii];
    f32x4 w0 = wp[(ii * 4 + 0) * 8];
    f32x4 w1 = wp[(ii * 4 + 1) * 8];
    f32x4 w2 = wp[(ii * 4 + 2) * 8];
    f32x4 w3 = wp[(ii * 4 + 3) * 8];
    a0 += ha[0] * w0; a1 += hb[0] * w0;
    a0 += ha[1] * w1; a1 += hb[1] * w1;
    a0 += ha[2] * w2; a1 += hb[2] * w2;
    a0 += ha[3] * w3; a1 += hb[3] * w3;
  }
#pragma unroll
  for (int j = 0; j < 4; ++j) {
    red[0][s][cg * 4 + j] = a0[j];
    red[1][s][cg * 4 + j] = a1[j];
  }
  // fused bf16 cast of hidden rows r0, r0+1 (L1-hot re-reads, coalesced 16B/lane)
  {
    int colb = s * 64 + cg * 8;
    const float* p0 = hidden + (long)r0 * D_ + colb;
    const float* p1 = p0 + D_;
    float4 x0 = *(const float4*)(p0);
    float4 x1 = *(const float4*)(p0 + 4);
    float4 y0 = *(const float4*)(p1);
    float4 y1 = *(const float4*)(p1 + 4);
    short8 o0, o1;
    o0[0] = f2bf(x0.x); o0[1] = f2bf(x0.y); o0[2] = f2bf(x0.z); o0[3] = f2bf(x0.w);
    o0[4] = f2bf(x1.x); o0[5] = f2bf(x1.y); o0[6] = f2bf(x1.z); o0[7] = f2bf(x1.w);
    o1[0] = f2bf(y0.x); o1[1] = f2bf(y0.y); o1[2] = f2bf(y0.z); o1[3] = f2bf(y0.w);
    o1[4] = f2bf(y1.x); o1[5] = f2bf(y1.y); o1[6] = f2bf(y1.z); o1[7] = f2bf(y1.w);
    *(short8*)(hbf + (long)r0 * D_ + colb) = o0;
    *(short8*)(hbf + (long)(r0 + 1) * D_ + colb) = o1;
  }
  __syncthreads();
  if (tid < 64) {
    int row = tid >> 5, c = tid & 31;
    float t0 = 0.f, t1 = 0.f, t2 = 0.f, t3 = 0.f;
#pragma unroll
    for (int ss = 0; ss < 32; ss += 4) {
      t0 += red[row][ss][c];
      t1 += red[row][ss + 1][c];
      t2 += red[row][ss + 2][c];
      t3 += red[row][ss + 3][c];
    }
    float t = (t0 + t1) + (t2 + t3);
    int r = r0 + row;
    if (c < 16) {
      betaT[c * BT_ + r] = 1.f / (1.f + __expf(-t));
    } else {
      int hh = c - 16;
      float y = t + dt_bias[hh];
      float sp = fmaxf(y, 0.f) + log1pf(__expf(-fabsf(y)));
      gT[hh * BT_ + r] = -__expf(A_log[hh]) * sp;   // raw g (log decay)
    }
  }
}

// ---------------- depthwise causal conv (K=4) + SiLU ----------------
__global__ void conv_silu(const float* __restrict__ x, const float* __restrict__ w,
                          float* __restrict__ y) {
  int idx = blockIdx.x * 256 + threadIdx.x;
  int c = idx & (CONV_DIM_ - 1);
  int bt = idx >> 12;
  int t = bt & (T_ - 1);
  float4 wc = *(const float4*)(w + c * 4);
  const float* xp = x + (long)idx;
  float acc = wc.w * xp[0];
  if (t >= 1) acc += wc.z * xp[-CONV_DIM_];
  if (t >= 2) acc += wc.y * xp[-2 * CONV_DIM_];
  if (t >= 3) acc += wc.x * xp[-3 * CONV_DIM_];
  y[idx] = acc * (1.f / (1.f + __expf(-acc)));
}

// ---------------- q/k l2norm (+ q scale), bf16 out ----------------
__global__ __launch_bounds__(64) void qknorm(const float* __restrict__ qkv,
                                             short* __restrict__ qb, short* __restrict__ kb) {
  int bi = blockIdx.x;          // B*T*HK*2
  int which = bi & 1;
  int h = (bi >> 1) & 7;
  int bt = bi >> 4;
  int lane = threadIdx.x;
  const float* src = qkv + (long)bt * CONV_DIM_ + which * KEY_DIM_ + h * DK_;
  float2 v = *(const float2*)(src + lane * 2);
  float ss = v.x * v.x + v.y * v.y;
#pragma unroll
  for (int m = 32; m; m >>= 1) ss += __shfl_xor(ss, m, 64);
  float scale = rsqrtf(ss + 1e-6f);
  if (which == 0) scale *= 0.08838834764831845f;  // DK^-0.5
  short* dst = (which ? kb : qb) + ((long)bt * HK_ + h) * DK_;
  short2 o; o.x = f2bf(v.x * scale); o.y = f2bf(v.y * scale);
  ((short2*)dst)[lane] = o;
}

// ================= PHASE 1: per-chunk local quantities (parallel, 512 blocks)
__global__ __launch_bounds__(256, 2) void chunk_phase1(
    const short* __restrict__ qbf, const short* __restrict__ kbf,
    const float* __restrict__ qkv, const float* __restrict__ gT,
    const float* __restrict__ bT,
    short* __restrict__ Pm, short* __restrict__ GQ, short* __restrict__ KtT,
    short* __restrict__ Wneg, float* __restrict__ Ut, float* __restrict__ Gammac) {
  __shared__ float Al[64 * 64];      // 16 KB
  __shared__ float Gs[64], Gam[64], Dd[64], Bet[64], BG[64];

  int ci = blockIdx.x;
  int c = ci & 15, hv = (ci >> 4) & 15, b = ci >> 8;
  int hk = hv >> 1;
  int t0 = c * CL_;
  int tid = threadIdx.x;
  int wave = tid >> 6, lane = tid & 63, quad = lane >> 4, l16 = lane & 15;

  if (tid < 64) {
    float g = gT[(hv * B_ + b) * T_ + t0 + tid];
    float x = g;
#pragma unroll
    for (int off = 1; off < 64; off <<= 1) {
      float y = __shfl_up(x, off, 64);
      if (tid >= off) x += y;
    }
    Gs[tid] = x;
    float gm = __expf(x);
    Gam[tid] = gm;
    float Gtot = __shfl(x, 63, 64);
    Dd[tid] = __expf(Gtot - x);
    float bb = bT[(hv * B_ + b) * T_ + t0 + tid];
    Bet[tid] = bb;
    BG[tid] = bb * gm;
    if (tid == 63) Gammac[ci] = __expf(x);
  }
  __syncthreads();

  const long kbase = ((long)(b * T_ + t0) * HK_ + hk) * DK_;   // in shorts
  const int kstride = HK_ * DK_;                               // 1024

  // ---- RHS columns into registers (coalesced: lane-consecutive cols) ----
  int half = tid >> 7;        // 0 = V-columns, 1 = betaGammaK-columns
  int col = tid & 127;
  float u[64];
  {
    const float* vcol = qkv + (long)(b * T_ + t0) * CONV_DIM_ + 2 * KEY_DIM_ + hv * DV_ + col;
    const short* kcol = kbf + kbase + col;
    if (half == 0) {
#pragma unroll
      for (int r = 0; r < 64; ++r) u[r] = vcol[(long)r * CONV_DIM_];
    } else {
#pragma unroll
      for (int r = 0; r < 64; ++r) u[r] = bf2f(kcol[(long)r * kstride]);
    }
  }

  // ---- KK^T -> Al (mask s>r, scale beta_s * exp(G_s - G_r)) ----
  {
    f32x4 acc[4] = {};
#pragma unroll
    for (int kk = 0; kk < 4; ++kk) {
      short8 afr = *(const short8*)(kbf + kbase + (long)(16 * wave + l16) * kstride + kk * 32 + quad * 8);
#pragma unroll
      for (int j = 0; j < 4; ++j) {
        short8 bfr = *(const short8*)(kbf + kbase + (long)(16 * j + l16) * kstride + kk * 32 + quad * 8);
        acc[j] = __builtin_amdgcn_mfma_f32_16x16x32_bf16(afr, bfr, acc[j], 0, 0, 0);
      }
    }
#pragma unroll
    for (int j = 0; j < 4; ++j)
#pragma unroll
      for (int r = 0; r < 4; ++r) {
        int row = 16 * wave + quad * 4 + r, colx = 16 * j + l16;
        float v = 0.f;
        if (row > colx) v = Bet[row] * __expf(Gs[row] - Gs[colx]) * acc[j][r];
        Al[row * 64 + colx] = v;
      }
  }
  // ---- QK^T -> Pm (mask t>=s, scale exp(G_t - G_s)) ----
  {
    f32x4 acc[4] = {};
#pragma unroll
    for (int kk = 0; kk < 4; ++kk) {
      short8 afr = *(const short8*)(qbf + kbase + (long)(16 * wave + l16) * kstride + kk * 32 + quad * 8);
#pragma unroll
      for (int j = 0; j < 4; ++j) {
        short8 bfr = *(const short8*)(kbf + kbase + (long)(16 * j + l16) * kstride + kk * 32 + quad * 8);
        acc[j] = __builtin_amdgcn_mfma_f32_16x16x32_bf16(afr, bfr, acc[j], 0, 0, 0);
      }
    }
#pragma unroll
    for (int j = 0; j < 4; ++j)
#pragma unroll
      for (int r = 0; r < 4; ++r) {
        int row = 16 * wave + quad * 4 + r, colx = 16 * j + l16;
        float v = 0.f;
        if (row >= colx) v = __expf(Gs[row] - Gs[colx]) * acc[j][r];
        Pm[(long)ci * 4096 + row * 64 + colx] = f2bf(v);
      }
  }
  // ---- GQ[s][d] = Gam[s]*q[s][d] (coalesced short2 writes) ----
  for (int s = wave; s < 64; s += 4) {
    float gm = Gam[s];
    short2 qv = *(const short2*)(qbf + kbase + (long)s * kstride + lane * 2);
    short2 o;
    o.x = f2bf(bf2f(qv.x) * gm);
    o.y = f2bf(bf2f(qv.y) * gm);
    *(short2*)(GQ + (long)ci * 8192 + s * 128 + lane * 2) = o;
  }
  // ---- KtT[d][s] = k[s][d]*Dd[s] ----
  for (int d = wave; d < 128; d += 4) {
    float kv = bf2f(kbf[kbase + (long)lane * kstride + d]);
    KtT[(long)ci * 8192 + d * 64 + lane] = f2bf(kv * Dd[lane]);
  }
  __syncthreads();   // Al complete

  // ---- scale RHS, register-resident forward substitution ----
  if (half == 0) {
#pragma unroll
    for (int r = 0; r < 64; ++r) u[r] *= Bet[r];
  } else {
#pragma unroll
    for (int r = 0; r < 64; ++r) u[r] *= BG[r];
  }
#pragma unroll
  for (int s = 1; s < 64; ++s) {
    const float* Ar = Al + s * 64;
    float acc = 0.f;
#pragma unroll
    for (int r4 = 0; r4 + 4 <= s; r4 += 4) {
      float4 a = *(const float4*)(Ar + r4);
      acc += (a.x * u[r4] + a.y * u[r4 + 1]) + (a.z * u[r4 + 2] + a.w * u[r4 + 3]);
    }
#pragma unroll
    for (int r = (s / 4) * 4; r < s; ++r) acc += Ar[r] * u[r];
    u[s] -= acc;
  }
  // ---- write out (coalesced) ----
  if (half == 0) {
    float* up = Ut + (long)ci * 8192 + col;
#pragma unroll
    for (int s = 0; s < 64; ++s) up[s * 128] = u[s];
  } else {
    short* wp = Wneg + (long)ci * 8192 + col;
#pragma unroll
    for (int s = 0; s < 64; ++s) wp[s * 128] = f2bf(-u[s]);
  }
}

// ================= PHASE 2: state recurrence over chunks (256 blocks) ========
__global__ __launch_bounds__(256) void chunk_phase2(
    const short* __restrict__ Wneg, const float* __restrict__ Ut,
    const short* __restrict__ KtT, const float* __restrict__ Gammac,
    short* __restrict__ UTg, short* __restrict__ ScTg) {
  __shared__ short SLT[16 * 136];   // S^T slice [n 16][m 128 pad 136]
  __shared__ short ULT[16 * 72];    // U'^T slice [n 16][s 64 pad 72]
  int bi = blockIdx.x >> 3;          // b*16+hv
  int n0 = (blockIdx.x & 7) * 16;    // col-slice base
  int tid = threadIdx.x, wave = tid >> 6, lane = tid & 63, quad = lane >> 4, l16 = lane & 15;
  f32x4 S2[2] = {};   // rows 32*wave+16i+quad*4+r, col n0+l16

  long ci0 = (long)bi * NCH_;
  // preload chunk-0 operands
  short8 Wr[4]; f32x4 Ur; short8 Kr[2][2];
  {
    long ci = ci0;
#pragma unroll
    for (int kk = 0; kk < 4; ++kk)
      Wr[kk] = *(const short8*)(Wneg + ci * 8192 + (16 * wave + l16) * 128 + kk * 32 + quad * 8);
    const float* up = Ut + ci * 8192 + (16 * wave + quad * 4) * 128 + n0 + l16;
#pragma unroll
    for (int r = 0; r < 4; ++r) Ur[r] = up[r * 128];
#pragma unroll
    for (int kk = 0; kk < 2; ++kk)
#pragma unroll
      for (int i = 0; i < 2; ++i)
        Kr[kk][i] = *(const short8*)(KtT + ci * 8192 + (32 * wave + 16 * i + l16) * 64 + kk * 32 + quad * 8);
  }

  for (int ch = 0; ch < NCH_; ++ch) {
    long ci = ci0 + ch;
    // 1. write S^T slice to LDS + global
#pragma unroll
    for (int i = 0; i < 2; ++i) {
      int m0 = 32 * wave + 16 * i + quad * 4;
      short4 p;
      p.x = f2bf(S2[i][0]); p.y = f2bf(S2[i][1]);
      p.z = f2bf(S2[i][2]); p.w = f2bf(S2[i][3]);
      *(short4*)(SLT + l16 * 136 + m0) = p;
      *(short4*)(ScTg + ci * 16384 + (n0 + l16) * 128 + m0) = p;
    }
    // prefetch next-chunk operands into registers (overlaps barriers + MFMA)
    short8 Wn[4]; f32x4 Un; short8 Kn[2][2];
    if (ch + 1 < NCH_) {
      long cj = ci + 1;
#pragma unroll
      for (int kk = 0; kk < 4; ++kk)
        Wn[kk] = *(const short8*)(Wneg + cj * 8192 + (16 * wave + l16) * 128 + kk * 32 + quad * 8);
      const float* up = Ut + cj * 8192 + (16 * wave + quad * 4) * 128 + n0 + l16;
#pragma unroll
      for (int r = 0; r < 4; ++r) Un[r] = up[r * 128];
#pragma unroll
      for (int kk = 0; kk < 2; ++kk)
#pragma unroll
        for (int i = 0; i < 2; ++i)
          Kn[kk][i] = *(const short8*)(KtT + cj * 8192 + (32 * wave + 16 * i + l16) * 64 + kk * 32 + quad * 8);
    }
    __syncthreads();
    // 2. U' = U - W @ S^T  (contraction over m=128)
    f32x4 Ua = Ur;
#pragma unroll
    for (int kk = 0; kk < 4; ++kk) {
      short8 bfv = *(const short8*)(SLT + l16 * 136 + kk * 32 + quad * 8);
      Ua = __builtin_amdgcn_mfma_f32_16x16x32_bf16(Wr[kk], bfv, Ua, 0, 0, 0);
    }
    {
      int s0 = 16 * wave + quad * 4;
      short4 p;
      p.x = f2bf(Ua[0]); p.y = f2bf(Ua[1]); p.z = f2bf(Ua[2]); p.w = f2bf(Ua[3]);
      *(short4*)(ULT + l16 * 72 + s0) = p;
      *(short4*)(UTg + ci * 8192 + (n0 + l16) * 64 + s0) = p;
    }
    __syncthreads();
    // 3. S = S*gamma + KtT @ U'^T  (contraction over s=64)
    float gc = Gammac[ci];
#pragma unroll
    for (int i = 0; i < 2; ++i)
#pragma unroll
      for (int r = 0; r < 4; ++r) S2[i][r] *= gc;
#pragma unroll
    for (int kk = 0; kk < 2; ++kk) {
      short8 bfv = *(const short8*)(ULT + l16 * 72 + kk * 32 + quad * 8);
#pragma unroll
      for (int i = 0; i < 2; ++i)
        S2[i] = __builtin_amdgcn_mfma_f32_16x16x32_bf16(Kr[kk][i], bfv, S2[i], 0, 0, 0);
    }
    __syncthreads();
    if (ch + 1 < NCH_) {
#pragma unroll
      for (int kk = 0; kk < 4; ++kk) Wr[kk] = Wn[kk];
      Ur = Un;
#pragma unroll
      for (int kk = 0; kk < 2; ++kk)
#pragma unroll
        for (int i = 0; i < 2; ++i) Kr[kk][i] = Kn[kk][i];
    }
  }
}

// ================= PHASE 3: outputs + fused gated RMSNorm (512 blocks) =======
__global__ __launch_bounds__(256) void chunk_phase3(
    const short* __restrict__ GQ, const short* __restrict__ ScTg,
    const short* __restrict__ Pm, const short* __restrict__ UTg,
    const float* __restrict__ zbuf, const float* __restrict__ nw,
    short* __restrict__ obf) {
  int ci = blockIdx.x;
  int c = ci & 15, hv = (ci >> 4) & 15, b = ci >> 8;
  int t0 = c * CL_;
  int tid = threadIdx.x, wave = tid >> 6, lane = tid & 63, quad = lane >> 4, l16 = lane & 15;
  f32x4 acc[8] = {};
#pragma unroll
  for (int kk = 0; kk < 4; ++kk) {
    short8 af = *(const short8*)(GQ + (long)ci * 8192 + (16 * wave + l16) * 128 + kk * 32 + quad * 8);
#pragma unroll
    for (int j = 0; j < 8; ++j) {
      short8 bfv = *(const short8*)(ScTg + (long)ci * 16384 + (16 * j + l16) * 128 + kk * 32 + quad * 8);
      acc[j] = __builtin_amdgcn_mfma_f32_16x16x32_bf16(af, bfv, acc[j], 0, 0, 0);
    }
  }
#pragma unroll
  for (int kk = 0; kk < 2; ++kk) {
    short8 af = *(const short8*)(Pm + (long)ci * 4096 + (16 * wave + l16) * 64 + kk * 32 + quad * 8);
#pragma unroll
    for (int j = 0; j < 8; ++j) {
      short8 bfv = *(const short8*)(UTg + (long)ci * 8192 + (16 * j + l16) * 64 + kk * 32 + quad * 8);
      acc[j] = __builtin_amdgcn_mfma_f32_16x16x32_bf16(af, bfv, acc[j], 0, 0, 0);
    }
  }
  // fused gated RMSNorm * silu(z) epilogue.
#pragma unroll
  for (int r = 0; r < 4; ++r) {
    float ss = 0.f;
#pragma unroll
    for (int j = 0; j < 8; ++j) ss += acc[j][r] * acc[j][r];
    ss += __shfl_xor(ss, 1, 64);
    ss += __shfl_xor(ss, 2, 64);
    ss += __shfl_xor(ss, 4, 64);
    ss += __shfl_xor(ss, 8, 64);
    float scale = rsqrtf(ss * (1.f / 128.f) + 1e-6f);
    int t = t0 + 16 * wave + quad * 4 + r;
    long base = (long)(b * T_ + t) * VALUE_DIM_ + hv * DV_;
#pragma unroll
    for (int j = 0; j < 8; ++j) {
      int n = 16 * j + l16;
      float zv = zbuf[base + n];
      float sz = zv * (1.f / (1.f + __expf(-zv)));
      obf[base + n] = f2bf(acc[j][r] * scale * nw[n] * sz);
    }
  }
}

// ---------------- launcher ----------------
extern "C" void kernel_launch(void* const* d_in, const int* in_sizes, int n_in,
                              void* d_out, int out_size, void* d_ws, size_t ws_size,
                              hipStream_t stream) {
  const float* hidden  = (const float*)d_in[0];
  const float* W_qkv   = (const float*)d_in[1];
  const float* W_z     = (const float*)d_in[2];
  const float* W_b     = (const float*)d_in[3];
  const float* W_a     = (const float*)d_in[4];
  const float* conv_w  = (const float*)d_in[5];
  const float* dt_bias = (const float*)d_in[6];
  const float* A_log   = (const float*)d_in[7];
  const float* norm_w  = (const float*)d_in[8];
  const float* W_out   = (const float*)d_in[9];
  float* out = (float*)d_out;

  char* ws = (char*)d_ws;
  size_t off = 0;
  auto alloc = [&](size_t bytes) {
    void* p = ws + off;
    off += (bytes + 255) & ~(size_t)255;
    return p;
  };
  short* hidden_bf = (short*)alloc((size_t)BT_ * D_ * 2);           // 8 MB
  short* WcatT     = (short*)alloc((size_t)(CONV_DIM_ + VALUE_DIM_) * D_ * 2); // 24 MB
  short* WoutT     = (short*)alloc((size_t)D_ * VALUE_DIM_ * 2);    // 8 MB
  float* mixed     = (float*)alloc((size_t)BT_ * CONV_DIM_ * 4);    // 32 MB
  float* qkv       = (float*)alloc((size_t)BT_ * CONV_DIM_ * 4);    // 32 MB
  float* zbuf      = (float*)alloc((size_t)BT_ * VALUE_DIM_ * 4);   // 16 MB
  short* qbf       = (short*)alloc((size_t)BT_ * KEY_DIM_ * 2);     // 4 MB
  short* kbf       = (short*)alloc((size_t)BT_ * KEY_DIM_ * 2);     // 4 MB
  float* betab     = (float*)alloc((size_t)BT_ * HV_ * 4);
  float* gb        = (float*)alloc((size_t)BT_ * HV_ * 4);
  float* Wba32     = (float*)alloc((size_t)D_ * 32 * 4);            // 256 KB
  short* Wneg      = (short*)alloc((size_t)512 * 8192 * 2);         // 8 MB
  float* Ut32      = (float*)alloc((size_t)512 * 8192 * 4);         // 16 MB
  short* KtT       = (short*)alloc((size_t)512 * 8192 * 2);         // 8 MB
  short* UTg       = (short*)alloc((size_t)512 * 8192 * 2);         // 8 MB
  short* ScTg      = (short*)alloc((size_t)512 * 16384 * 2);        // 16 MB
  float* Gammac    = (float*)alloc((size_t)512 * 4);
  // aliases (into buffers dead by the time they're written):
  short* Pm   = (short*)(mixed + (size_t)BT_ * VALUE_DIM_);         // 4 MB (mixed dead after conv)
  short* GQ   = Pm + (size_t)512 * 4096;                            // 8 MB
  short* obf  = hidden_bf;          // dead after fused qkv+z GEMM
  float* Cpart = qkv;               // 32 MB; qkv dead after phase1 (split-K partials)

  dim3 tb32(32, 8);
  transpose_cast<<<dim3(CONV_DIM_ / 32, D_ / 32), tb32, 0, stream>>>(W_qkv, WcatT, D_, CONV_DIM_);
  transpose_cast<<<dim3(VALUE_DIM_ / 32, D_ / 32), tb32, 0, stream>>>(W_z, WcatT + (size_t)CONV_DIM_ * D_, D_, VALUE_DIM_);
  transpose_cast<<<dim3(D_ / 32, VALUE_DIM_ / 32), tb32, 0, stream>>>(W_out, WoutT, VALUE_DIM_, D_);
  interleave_ba<<<32 * D_ / 256, 256, 0, stream>>>(W_b, W_a, Wba32);

  // beta/g projections + fused hidden bf16 cast (must precede the GEMM)
  small_proj<<<BT_ / 2, 256, 0, stream>>>(hidden, Wba32, dt_bias, A_log, betab, gb, hidden_bf);

  // fused qkv + z projection: 256x256 8-phase, N = 6144, grid 24x8 = 192 blocks
  gemm256_split<<<dim3((CONV_DIM_ + VALUE_DIM_) / 256, BT_ / 256), 512, 0, stream>>>(
      hidden_bf, WcatT, mixed, zbuf, CONV_DIM_, VALUE_DIM_, D_);
  conv_silu<<<BT_ * CONV_DIM_ / 256, 256, 0, stream>>>(mixed, conv_w, qkv);
  qknorm<<<BT_ * HK_ * 2, 64, 0, stream>>>(qkv, qbf, kbf);

  chunk_phase1<<<512, 256, 0, stream>>>(qbf, kbf, qkv, gb, betab, Pm, GQ, KtT, Wneg, Ut32, Gammac);
  chunk_phase2<<<256, 256, 0, stream>>>(Wneg, Ut32, KtT, Gammac, UTg, ScTg);
  chunk_phase3<<<512, 256, 0, stream>>>(GQ, ScTg, Pm, UTg, zbuf, norm_w, obf);

  // out projection: split-K=2 -> 512 blocks (2 blk/CU), then partial-sum
  gemm128_ks<<<dim3(D_ / 128, BT_ / 128, 2), 256, 0, stream>>>(obf, WoutT, Cpart, BT_, D_, VALUE_DIM_);
  add2<<<(BT_ * D_ / 4 + 255) / 256, 256, 0, stream>>>(Cpart, Cpart + (size_t)BT_ * D_, out, BT_ * D_ / 4);
}

// Round 4
// 364.905 us; speedup vs baseline: 1.0392x; 1.0392x over previous
//
#include <hip/hip_runtime.h>
#include <hip/hip_bf16.h>

// GatedDeltaNet: B=2, T=1024, D=2048, HK=8, HV=16, DK=DV=128, KW=4
#define B_ 2
#define T_ 1024
#define D_ 2048
#define HK_ 8
#define HV_ 16
#define DK_ 128
#define DV_ 128
#define KEY_DIM_ 1024
#define VALUE_DIM_ 2048
#define CONV_DIM_ 4096
#define BT_ 2048   // B*T
#define NCH_ 16    // chunks per sequence (T/64)
#define CL_ 64     // chunk length

typedef __attribute__((ext_vector_type(8))) short short8;
typedef __attribute__((ext_vector_type(4))) float f32x4;

__device__ __forceinline__ short f2bf(float x) {
  __hip_bfloat16 h = __float2bfloat16(x);
  return *reinterpret_cast<short*>(&h);
}
__device__ __forceinline__ float bf2f(short u) {
  unsigned int x = ((unsigned int)(unsigned short)u) << 16;
  return __int_as_float(x);
}

#define GLOAD_LDS16(g, l)                                             \
  __builtin_amdgcn_global_load_lds(                                   \
      (const __attribute__((address_space(1))) void*)(g),             \
      (__attribute__((address_space(3))) void*)(l), 16, 0, 0)

// ---------------- transpose + cast: W[R,C] f32 -> WT[C,R] bf16 ----------------
__global__ void transpose_cast(const float* __restrict__ W, short* __restrict__ WT, int R, int C) {
  __shared__ float tile[32][33];
  int tx = threadIdx.x, ty = threadIdx.y;
  int x = blockIdx.x * 32 + tx;
#pragma unroll
  for (int j = 0; j < 4; ++j) {
    int r = blockIdx.y * 32 + ty + j * 8;
    tile[ty + j * 8][tx] = W[(long)r * C + x];
  }
  __syncthreads();
  int ro = blockIdx.y * 32 + tx;
#pragma unroll
  for (int j = 0; j < 4; ++j) {
    int co = blockIdx.x * 32 + ty + j * 8;
    WT[(long)co * R + ro] = f2bf(tile[tx][ty + j * 8]);
  }
}

// ---------------- W_b|W_a -> Wba32[k][32] (k-major interleave) ----------------
__global__ void interleave_ba(const float* __restrict__ Wb, const float* __restrict__ Wa,
                              float* __restrict__ Wba32) {
  int i = blockIdx.x * 256 + threadIdx.x;   // D*32
  int c = i & 31, k = i >> 5;
  Wba32[i] = (c < 16) ? Wb[k * 16 + c] : Wa[k * 16 + (c - 16)];
}

#define MFMA_(d, x, y) d = __builtin_amdgcn_mfma_f32_16x16x32_bf16(x, y, d, 0, 0, 0)
#define BAR_() do { __builtin_amdgcn_s_barrier(); __builtin_amdgcn_sched_barrier(0); } while (0)
#define PRIO_ON_() __builtin_amdgcn_s_setprio(1)
#define PRIO_OFF_() do { __builtin_amdgcn_s_setprio(0); __builtin_amdgcn_sched_barrier(0); } while (0)

// ========== 256x192 8-phase GEMM (grid 32x8 = 256 blocks = 1/CU) ============
// BM=256, BN=192, BK=64, 8 waves (4M x 2N, per-wave 64x96). LDS 112 KB.
// 7 load-units/tile: A rb{0,64,128,192}, B rb{0,64,128}. vmcnt(6) at epoch ends.
// Output straddle: per-element C0/C1 select at the 4096 boundary.
__global__ __launch_bounds__(512) void gemm256n192(const short* __restrict__ A,
                                                   const short* __restrict__ Bt,
                                                   float* __restrict__ C0,
                                                   float* __restrict__ C1,
                                                   int N0, int N1, int K) {
  __shared__ short lds[57344];   // 2 bufs x 28672 shorts (A 16384 | B 12288)
  const int tid = threadIdx.x;
  const int lane = tid & 63, wid = tid >> 6;
  const int quad = lane >> 4, l16 = lane & 15;
  const int wm = (wid >> 1) * 64, wn = (wid & 1) * 96;
  const int m0 = blockIdx.y * 256, n0 = blockIdx.x * 192;

  const int r8 = tid >> 3, t8 = (tid & 7) * 8;
  const int csw = t8 ^ ((r8 & 7) << 3);
  const int cswr = (quad ^ (l16 & 7)) << 3;
  const int NIT = K >> 7;   // 2 K-tiles per iteration

  f32x4 acc[4][6] = {};
  short8 a[4][2], bl[3][2], bh[3][2];

#define SGA(p, kt, rb) GLOAD_LDS16(A + (long)(m0 + (rb) + r8) * K + (kt) * 64 + csw, \
                                   lds + (p) * 28672 + ((rb) + r8) * 64 + t8)
#define SGB(p, kt, rb) GLOAD_LDS16(Bt + (long)(n0 + (rb) + r8) * K + (kt) * 64 + csw, \
                                   lds + (p) * 28672 + 16384 + ((rb) + r8) * 64 + t8)
#define RDA(p, r, kk) (*(const short8*)(lds + (p) * 28672 + (r) * 64 + (cswr ^ ((kk) << 5))))
#define RDB(p, r, kk) (*(const short8*)(lds + (p) * 28672 + 16384 + (r) * 64 + (cswr ^ ((kk) << 5))))

  // prologue: tile0 full (7), tile1 minus last B unit (6) -> 13 outstanding
  SGA(0, 0, 0); SGA(0, 0, 64); SGA(0, 0, 128); SGA(0, 0, 192);
  SGB(0, 0, 0); SGB(0, 0, 64); SGB(0, 0, 128);
  SGA(1, 1, 0); SGA(1, 1, 64); SGA(1, 1, 128); SGA(1, 1, 192);
  SGB(1, 1, 0); SGB(1, 1, 64);
  asm volatile("s_waitcnt vmcnt(6)" ::: "memory");
  BAR_();

#pragma unroll 1
  for (int i = 0; i < NIT; ++i) {
    const int tb = 2 * i + 1, tc = 2 * i + 2, td = 2 * i + 3;
    const bool more = (i + 1 < NIT);

    // ---- ph1: buf0, m01 x n-lo ----
#pragma unroll
    for (int mi = 0; mi < 2; ++mi) {
      a[mi][0] = RDA(0, wm + mi * 16 + l16, 0);
      a[mi][1] = RDA(0, wm + mi * 16 + l16, 1);
    }
#pragma unroll
    for (int ni = 0; ni < 3; ++ni) {
      bl[ni][0] = RDB(0, wn + ni * 16 + l16, 0);
      bl[ni][1] = RDB(0, wn + ni * 16 + l16, 1);
    }
    SGB(1, tb, 128);           // deferred last B unit of tile tb (buf1)
    BAR_();
    PRIO_ON_();
#pragma unroll
    for (int mi = 0; mi < 2; ++mi)
#pragma unroll
      for (int ni = 0; ni < 3; ++ni) {
        MFMA_(acc[mi][ni], a[mi][0], bl[ni][0]);
        MFMA_(acc[mi][ni], a[mi][1], bl[ni][1]);
      }
    PRIO_OFF_();
    __builtin_amdgcn_s_barrier();

    // ---- ph2: buf0, m23 x n-lo ----
    __builtin_amdgcn_sched_barrier(0);
#pragma unroll
    for (int mi = 2; mi < 4; ++mi) {
      a[mi][0] = RDA(0, wm + mi * 16 + l16, 0);
      a[mi][1] = RDA(0, wm + mi * 16 + l16, 1);
    }
    BAR_();
    PRIO_ON_();
#pragma unroll
    for (int mi = 2; mi < 4; ++mi)
#pragma unroll
      for (int ni = 0; ni < 3; ++ni) {
        MFMA_(acc[mi][ni], a[mi][0], bl[ni][0]);
        MFMA_(acc[mi][ni], a[mi][1], bl[ni][1]);
      }
    PRIO_OFF_();
    __builtin_amdgcn_s_barrier();

    // ---- ph3: buf0, m01 x n-hi (A reads of buf0 done -> stage A into buf0) --
    __builtin_amdgcn_sched_barrier(0);
#pragma unroll
    for (int ni = 0; ni < 3; ++ni) {
      bh[ni][0] = RDB(0, wn + 48 + ni * 16 + l16, 0);
      bh[ni][1] = RDB(0, wn + 48 + ni * 16 + l16, 1);
    }
    if (more) { SGA(0, tc, 0); SGA(0, tc, 64); }
    BAR_();
    PRIO_ON_();
#pragma unroll
    for (int mi = 0; mi < 2; ++mi)
#pragma unroll
      for (int ni = 0; ni < 3; ++ni) {
        MFMA_(acc[mi][3 + ni], a[mi][0], bh[ni][0]);
        MFMA_(acc[mi][3 + ni], a[mi][1], bh[ni][1]);
      }
    PRIO_OFF_();
    __builtin_amdgcn_s_barrier();

    // ---- ph4: buf0, m23 x n-hi (B reads done -> stage rest into buf0) ----
    __builtin_amdgcn_sched_barrier(0);
    if (more) { SGA(0, tc, 128); SGA(0, tc, 192); SGB(0, tc, 0); SGB(0, tc, 64); }
    BAR_();
    PRIO_ON_();
#pragma unroll
    for (int mi = 2; mi < 4; ++mi)
#pragma unroll
      for (int ni = 0; ni < 3; ++ni) {
        MFMA_(acc[mi][3 + ni], a[mi][0], bh[ni][0]);
        MFMA_(acc[mi][3 + ni], a[mi][1], bh[ni][1]);
      }
    PRIO_OFF_();
    if (more) { asm volatile("s_waitcnt vmcnt(6)" ::: "memory"); }
    else      { asm volatile("s_waitcnt vmcnt(0)" ::: "memory"); }
    __builtin_amdgcn_s_barrier();

    // ---- ph5: buf1, m01 x n-lo ----
    __builtin_amdgcn_sched_barrier(0);
#pragma unroll
    for (int mi = 0; mi < 2; ++mi) {
      a[mi][0] = RDA(1, wm + mi * 16 + l16, 0);
      a[mi][1] = RDA(1, wm + mi * 16 + l16, 1);
    }
#pragma unroll
    for (int ni = 0; ni < 3; ++ni) {
      bl[ni][0] = RDB(1, wn + ni * 16 + l16, 0);
      bl[ni][1] = RDB(1, wn + ni * 16 + l16, 1);
    }
    if (more) SGB(0, tc, 128);
    BAR_();
    PRIO_ON_();
#pragma unroll
    for (int mi = 0; mi < 2; ++mi)
#pragma unroll
      for (int ni = 0; ni < 3; ++ni) {
        MFMA_(acc[mi][ni], a[mi][0], bl[ni][0]);
        MFMA_(acc[mi][ni], a[mi][1], bl[ni][1]);
      }
    PRIO_OFF_();
    __builtin_amdgcn_s_barrier();

    // ---- ph6: buf1, m23 x n-lo ----
    __builtin_amdgcn_sched_barrier(0);
#pragma unroll
    for (int mi = 2; mi < 4; ++mi) {
      a[mi][0] = RDA(1, wm + mi * 16 + l16, 0);
      a[mi][1] = RDA(1, wm + mi * 16 + l16, 1);
    }
    BAR_();
    PRIO_ON_();
#pragma unroll
    for (int mi = 2; mi < 4; ++mi)
#pragma unroll
      for (int ni = 0; ni < 3; ++ni) {
        MFMA_(acc[mi][ni], a[mi][0], bl[ni][0]);
        MFMA_(acc[mi][ni], a[mi][1], bl[ni][1]);
      }
    PRIO_OFF_();
    __builtin_amdgcn_s_barrier();

    // ---- ph7: buf1, m01 x n-hi ----
    __builtin_amdgcn_sched_barrier(0);
#pragma unroll
    for (int ni = 0; ni < 3; ++ni) {
      bh[ni][0] = RDB(1, wn + 48 + ni * 16 + l16, 0);
      bh[ni][1] = RDB(1, wn + 48 + ni * 16 + l16, 1);
    }
    if (more) { SGA(1, td, 0); SGA(1, td, 64); }
    BAR_();
    PRIO_ON_();
#pragma unroll
    for (int mi = 0; mi < 2; ++mi)
#pragma unroll
      for (int ni = 0; ni < 3; ++ni) {
        MFMA_(acc[mi][3 + ni], a[mi][0], bh[ni][0]);
        MFMA_(acc[mi][3 + ni], a[mi][1], bh[ni][1]);
      }
    PRIO_OFF_();
    __builtin_amdgcn_s_barrier();

    // ---- ph8: buf1, m23 x n-hi ----
    __builtin_amdgcn_sched_barrier(0);
    if (more) { SGA(1, td, 128); SGA(1, td, 192); SGB(1, td, 0); SGB(1, td, 64); }
    BAR_();
    PRIO_ON_();
#pragma unroll
    for (int mi = 2; mi < 4; ++mi)
#pragma unroll
      for (int ni = 0; ni < 3; ++ni) {
        MFMA_(acc[mi][3 + ni], a[mi][0], bh[ni][0]);
        MFMA_(acc[mi][3 + ni], a[mi][1], bh[ni][1]);
      }
    PRIO_OFF_();
    if (more) { asm volatile("s_waitcnt vmcnt(6)" ::: "memory"); }
    else      { asm volatile("s_waitcnt vmcnt(0)" ::: "memory"); }
    __builtin_amdgcn_s_barrier();
    __builtin_amdgcn_sched_barrier(0);
  }

#pragma unroll
  for (int mi = 0; mi < 4; ++mi)
#pragma unroll
    for (int ni = 0; ni < 6; ++ni)
#pragma unroll
      for (int r = 0; r < 4; ++r) {
        int row = m0 + wm + mi * 16 + quad * 4 + r;
        int col = n0 + wn + ni * 16 + l16;
        if (col < N0) C0[(long)row * N0 + col] = acc[mi][ni][r];
        else          C1[(long)row * N1 + (col - N0)] = acc[mi][ni][r];
      }
#undef SGA
#undef SGB
#undef RDA
#undef RDB
}

// ========== 256x128 8-phase GEMM, split-K=2 (grid 16x8x2 = 256 blocks) ======
// BM=256, BN=128, BK=64, 8 waves (4M x 2N, per-wave 64x64). LDS 96 KB.
// 6 load-units/tile: A rb{0,64,128,192}, B rb{0,64}. vmcnt(5) at epoch ends.
__global__ __launch_bounds__(512) void gemm256ks(const short* __restrict__ Ag,
                                                 const short* __restrict__ Btg,
                                                 float* __restrict__ Cp,
                                                 int M, int N, int K) {
  __shared__ short lds[49152];   // 2 bufs x 24576 shorts (A 16384 | B 8192)
  const int tid = threadIdx.x;
  const int lane = tid & 63, wid = tid >> 6;
  const int quad = lane >> 4, l16 = lane & 15;
  const int wm = (wid >> 1) * 64, wn = (wid & 1) * 64;
  const int m0 = blockIdx.y * 256, n0 = blockIdx.x * 128;
  const int kh = K >> 1;
  const short* A = Ag + blockIdx.z * kh;    // column offset into K
  const short* Bt = Btg + blockIdx.z * kh;

  const int r8 = tid >> 3, t8 = (tid & 7) * 8;
  const int csw = t8 ^ ((r8 & 7) << 3);
  const int cswr = (quad ^ (l16 & 7)) << 3;
  const int NIT = kh >> 7;

  f32x4 acc[4][4] = {};
  short8 a[4][2], bl[2][2], bh[2][2];

#define SGA(p, kt, rb) GLOAD_LDS16(A + (long)(m0 + (rb) + r8) * K + (kt) * 64 + csw, \
                                   lds + (p) * 24576 + ((rb) + r8) * 64 + t8)
#define SGB(p, kt, rb) GLOAD_LDS16(Bt + (long)(n0 + (rb) + r8) * K + (kt) * 64 + csw, \
                                   lds + (p) * 24576 + 16384 + ((rb) + r8) * 64 + t8)
#define RDA(p, r, kk) (*(const short8*)(lds + (p) * 24576 + (r) * 64 + (cswr ^ ((kk) << 5))))
#define RDB(p, r, kk) (*(const short8*)(lds + (p) * 24576 + 16384 + (r) * 64 + (cswr ^ ((kk) << 5))))

  // prologue: tile0 full (6), tile1 minus last B unit (5) -> 11 outstanding
  SGA(0, 0, 0); SGA(0, 0, 64); SGA(0, 0, 128); SGA(0, 0, 192);
  SGB(0, 0, 0); SGB(0, 0, 64);
  SGA(1, 1, 0); SGA(1, 1, 64); SGA(1, 1, 128); SGA(1, 1, 192);
  SGB(1, 1, 0);
  asm volatile("s_waitcnt vmcnt(5)" ::: "memory");
  BAR_();

#pragma unroll 1
  for (int i = 0; i < NIT; ++i) {
    const int tb = 2 * i + 1, tc = 2 * i + 2, td = 2 * i + 3;
    const bool more = (i + 1 < NIT);

    // ---- ph1 ----
#pragma unroll
    for (int mi = 0; mi < 2; ++mi) {
      a[mi][0] = RDA(0, wm + mi * 16 + l16, 0);
      a[mi][1] = RDA(0, wm + mi * 16 + l16, 1);
    }
#pragma unroll
    for (int ni = 0; ni < 2; ++ni) {
      bl[ni][0] = RDB(0, wn + ni * 16 + l16, 0);
      bl[ni][1] = RDB(0, wn + ni * 16 + l16, 1);
    }
    SGB(1, tb, 64);
    BAR_();
    PRIO_ON_();
#pragma unroll
    for (int mi = 0; mi < 2; ++mi)
#pragma unroll
      for (int ni = 0; ni < 2; ++ni) {
        MFMA_(acc[mi][ni], a[mi][0], bl[ni][0]);
        MFMA_(acc[mi][ni], a[mi][1], bl[ni][1]);
      }
    PRIO_OFF_();
    __builtin_amdgcn_s_barrier();

    // ---- ph2 ----
    __builtin_amdgcn_sched_barrier(0);
#pragma unroll
    for (int mi = 2; mi < 4; ++mi) {
      a[mi][0] = RDA(0, wm + mi * 16 + l16, 0);
      a[mi][1] = RDA(0, wm + mi * 16 + l16, 1);
    }
    BAR_();
    PRIO_ON_();
#pragma unroll
    for (int mi = 2; mi < 4; ++mi)
#pragma unroll
      for (int ni = 0; ni < 2; ++ni) {
        MFMA_(acc[mi][ni], a[mi][0], bl[ni][0]);
        MFMA_(acc[mi][ni], a[mi][1], bl[ni][1]);
      }
    PRIO_OFF_();
    __builtin_amdgcn_s_barrier();

    // ---- ph3 ----
    __builtin_amdgcn_sched_barrier(0);
#pragma unroll
    for (int ni = 0; ni < 2; ++ni) {
      bh[ni][0] = RDB(0, wn + 32 + ni * 16 + l16, 0);
      bh[ni][1] = RDB(0, wn + 32 + ni * 16 + l16, 1);
    }
    if (more) { SGA(0, tc, 0); SGA(0, tc, 64); }
    BAR_();
    PRIO_ON_();
#pragma unroll
    for (int mi = 0; mi < 2; ++mi)
#pragma unroll
      for (int ni = 0; ni < 2; ++ni) {
        MFMA_(acc[mi][2 + ni], a[mi][0], bh[ni][0]);
        MFMA_(acc[mi][2 + ni], a[mi][1], bh[ni][1]);
      }
    PRIO_OFF_();
    __builtin_amdgcn_s_barrier();

    // ---- ph4 ----
    __builtin_amdgcn_sched_barrier(0);
    if (more) { SGA(0, tc, 128); SGA(0, tc, 192); SGB(0, tc, 0); }
    BAR_();
    PRIO_ON_();
#pragma unroll
    for (int mi = 2; mi < 4; ++mi)
#pragma unroll
      for (int ni = 0; ni < 2; ++ni) {
        MFMA_(acc[mi][2 + ni], a[mi][0], bh[ni][0]);
        MFMA_(acc[mi][2 + ni], a[mi][1], bh[ni][1]);
      }
    PRIO_OFF_();
    if (more) { asm volatile("s_waitcnt vmcnt(5)" ::: "memory"); }
    else      { asm volatile("s_waitcnt vmcnt(0)" ::: "memory"); }
    __builtin_amdgcn_s_barrier();

    // ---- ph5 ----
    __builtin_amdgcn_sched_barrier(0);
#pragma unroll
    for (int mi = 0; mi < 2; ++mi) {
      a[mi][0] = RDA(1, wm + mi * 16 + l16, 0);
      a[mi][1] = RDA(1, wm + mi * 16 + l16, 1);
    }
#pragma unroll
    for (int ni = 0; ni < 2; ++ni) {
      bl[ni][0] = RDB(1, wn + ni * 16 + l16, 0);
      bl[ni][1] = RDB(1, wn + ni * 16 + l16, 1);
    }
    if (more) SGB(0, tc, 64);
    BAR_();
    PRIO_ON_();
#pragma unroll
    for (int mi = 0; mi < 2; ++mi)
#pragma unroll
      for (int ni = 0; ni < 2; ++ni) {
        MFMA_(acc[mi][ni], a[mi][0], bl[ni][0]);
        MFMA_(acc[mi][ni], a[mi][1], bl[ni][1]);
      }
    PRIO_OFF_();
    __builtin_amdgcn_s_barrier();

    // ---- ph6 ----
    __builtin_amdgcn_sched_barrier(0);
#pragma unroll
    for (int mi = 2; mi < 4; ++mi) {
      a[mi][0] = RDA(1, wm + mi * 16 + l16, 0);
      a[mi][1] = RDA(1, wm + mi * 16 + l16, 1);
    }
    BAR_();
    PRIO_ON_();
#pragma unroll
    for (int mi = 2; mi < 4; ++mi)
#pragma unroll
      for (int ni = 0; ni < 2; ++ni) {
        MFMA_(acc[mi][ni], a[mi][0], bl[ni][0]);
        MFMA_(acc[mi][ni], a[mi][1], bl[ni][1]);
      }
    PRIO_OFF_();
    __builtin_amdgcn_s_barrier();

    // ---- ph7 ----
    __builtin_amdgcn_sched_barrier(0);
#pragma unroll
    for (int ni = 0; ni < 2; ++ni) {
      bh[ni][0] = RDB(1, wn + 32 + ni * 16 + l16, 0);
      bh[ni][1] = RDB(1, wn + 32 + ni * 16 + l16, 1);
    }
    if (more) { SGA(1, td, 0); SGA(1, td, 64); }
    BAR_();
    PRIO_ON_();
#pragma unroll
    for (int mi = 0; mi < 2; ++mi)
#pragma unroll
      for (int ni = 0; ni < 2; ++ni) {
        MFMA_(acc[mi][2 + ni], a[mi][0], bh[ni][0]);
        MFMA_(acc[mi][2 + ni], a[mi][1], bh[ni][1]);
      }
    PRIO_OFF_();
    __builtin_amdgcn_s_barrier();

    // ---- ph8 ----
    __builtin_amdgcn_sched_barrier(0);
    if (more) { SGA(1, td, 128); SGA(1, td, 192); SGB(1, td, 0); }
    BAR_();
    PRIO_ON_();
#pragma unroll
    for (int mi = 2; mi < 4; ++mi)
#pragma unroll
      for (int ni = 0; ni < 2; ++ni) {
        MFMA_(acc[mi][2 + ni], a[mi][0], bh[ni][0]);
        MFMA_(acc[mi][2 + ni], a[mi][1], bh[ni][1]);
      }
    PRIO_OFF_();
    if (more) { asm volatile("s_waitcnt vmcnt(5)" ::: "memory"); }
    else      { asm volatile("s_waitcnt vmcnt(0)" ::: "memory"); }
    __builtin_amdgcn_s_barrier();
    __builtin_amdgcn_sched_barrier(0);
  }

  float* Cz = Cp + (long)blockIdx.z * M * N;
#pragma unroll
  for (int mi = 0; mi < 4; ++mi)
#pragma unroll
    for (int ni = 0; ni < 4; ++ni)
#pragma unroll
      for (int r = 0; r < 4; ++r) {
        int row = m0 + wm + mi * 16 + quad * 4 + r;
        int col = n0 + wn + ni * 16 + l16;
        Cz[(long)row * N + col] = acc[mi][ni][r];
      }
#undef SGA
#undef SGB
#undef RDA
#undef RDB
}

// ---------------- sum two split-K partials ----------------
__global__ void add2(const float* __restrict__ p0, const float* __restrict__ p1,
                     float* __restrict__ out, int n4) {
  int i = blockIdx.x * 256 + threadIdx.x;
  if (i < n4) {
    float4 a = ((const float4*)p0)[i];
    float4 b = ((const float4*)p1)[i];
    float4 o;
    o.x = a.x + b.x; o.y = a.y + b.y; o.z = a.z + b.z; o.w = a.w + b.w;
    ((float4*)out)[i] = o;
  }
}

// ---------------- beta / g projections + fused hidden bf16 cast --------------
__global__ __launch_bounds__(256) void small_proj(const float* __restrict__ hidden,
                                                  const float* __restrict__ Wba32,
                                                  const float* __restrict__ dt_bias,
                                                  const float* __restrict__ A_log,
                                                  float* __restrict__ betaT,
                                                  float* __restrict__ gT,
                                                  short* __restrict__ hbf) {
  __shared__ float red[2][32][33];
  int r0 = blockIdx.x * 2;
  int tid = threadIdx.x;
  int cg = tid & 7, s = tid >> 3;
  const f32x4* wp = (const f32x4*)Wba32 + (long)s * 64 * 8 + cg;
  const f32x4* h0 = (const f32x4*)(hidden + (long)r0 * D_ + s * 64);
  const f32x4* h1 = (const f32x4*)(hidden + (long)(r0 + 1) * D_ + s * 64);
  f32x4 a0 = {0.f, 0.f, 0.f, 0.f}, a1 = {0.f, 0.f, 0.f, 0.f};
#pragma unroll
  for (int ii = 0; ii < 16; ++ii) {
    f32x4 ha = h0[ii], hb = h1[ii];
    f32x4 w0 = wp[(ii * 4 + 0) * 8];
    f32x4 w1 = wp[(ii * 4 + 1) * 8];
    f32x4 w2 = wp[(ii * 4 + 2) * 8];
    f32x4 w3 = wp[(ii * 4 + 3) * 8];
    a0 += ha[0] * w0; a1 += hb[0] * w0;
    a0 += ha[1] * w1; a1 += hb[1] * w1;
    a0 += ha[2] * w2; a1 += hb[2] * w2;
    a0 += ha[3] * w3; a1 += hb[3] * w3;
  }
#pragma unroll
  for (int j = 0; j < 4; ++j) {
    red[0][s][cg * 4 + j] = a0[j];
    red[1][s][cg * 4 + j] = a1[j];
  }
  // fused bf16 cast of hidden rows r0, r0+1 (L1-hot re-reads, coalesced 16B/lane)
  {
    int colb = s * 64 + cg * 8;
    const float* p0 = hidden + (long)r0 * D_ + colb;
    const float* p1 = p0 + D_;
    float4 x0 = *(const float4*)(p0);
    float4 x1 = *(const float4*)(p0 + 4);
    float4 y0 = *(const float4*)(p1);
    float4 y1 = *(const float4*)(p1 + 4);
    short8 o0, o1;
    o0[0] = f2bf(x0.x); o0[1] = f2bf(x0.y); o0[2] = f2bf(x0.z); o0[3] = f2bf(x0.w);
    o0[4] = f2bf(x1.x); o0[5] = f2bf(x1.y); o0[6] = f2bf(x1.z); o0[7] = f2bf(x1.w);
    o1[0] = f2bf(y0.x); o1[1] = f2bf(y0.y); o1[2] = f2bf(y0.z); o1[3] = f2bf(y0.w);
    o1[4] = f2bf(y1.x); o1[5] = f2bf(y1.y); o1[6] = f2bf(y1.z); o1[7] = f2bf(y1.w);
    *(short8*)(hbf + (long)r0 * D_ + colb) = o0;
    *(short8*)(hbf + (long)(r0 + 1) * D_ + colb) = o1;
  }
  __syncthreads();
  if (tid < 64) {
    int row = tid >> 5, c = tid & 31;
    float t0 = 0.f, t1 = 0.f, t2 = 0.f, t3 = 0.f;
#pragma unroll
    for (int ss = 0; ss < 32; ss += 4) {
      t0 += red[row][ss][c];
      t1 += red[row][ss + 1][c];
      t2 += red[row][ss + 2][c];
      t3 += red[row][ss + 3][c];
    }
    float t = (t0 + t1) + (t2 + t3);
    int r = r0 + row;
    if (c < 16) {
      betaT[c * BT_ + r] = 1.f / (1.f + __expf(-t));
    } else {
      int hh = c - 16;
      float y = t + dt_bias[hh];
      float sp = fmaxf(y, 0.f) + log1pf(__expf(-fabsf(y)));
      gT[hh * BT_ + r] = -__expf(A_log[hh]) * sp;   // raw g (log decay)
    }
  }
}

// ---------------- depthwise causal conv (K=4) + SiLU ----------------
__global__ void conv_silu(const float* __restrict__ x, const float* __restrict__ w,
                          float* __restrict__ y) {
  int idx = blockIdx.x * 256 + threadIdx.x;
  int c = idx & (CONV_DIM_ - 1);
  int bt = idx >> 12;
  int t = bt & (T_ - 1);
  float4 wc = *(const float4*)(w + c * 4);
  const float* xp = x + (long)idx;
  float acc = wc.w * xp[0];
  if (t >= 1) acc += wc.z * xp[-CONV_DIM_];
  if (t >= 2) acc += wc.y * xp[-2 * CONV_DIM_];
  if (t >= 3) acc += wc.x * xp[-3 * CONV_DIM_];
  y[idx] = acc * (1.f / (1.f + __expf(-acc)));
}

// ---------------- q/k l2norm (+ q scale), bf16 out ----------------
__global__ __launch_bounds__(64) void qknorm(const float* __restrict__ qkv,
                                             short* __restrict__ qb, short* __restrict__ kb) {
  int bi = blockIdx.x;          // B*T*HK*2
  int which = bi & 1;
  int h = (bi >> 1) & 7;
  int bt = bi >> 4;
  int lane = threadIdx.x;
  const float* src = qkv + (long)bt * CONV_DIM_ + which * KEY_DIM_ + h * DK_;
  float2 v = *(const float2*)(src + lane * 2);
  float ss = v.x * v.x + v.y * v.y;
#pragma unroll
  for (int m = 32; m; m >>= 1) ss += __shfl_xor(ss, m, 64);
  float scale = rsqrtf(ss + 1e-6f);
  if (which == 0) scale *= 0.08838834764831845f;  // DK^-0.5
  short* dst = (which ? kb : qb) + ((long)bt * HK_ + h) * DK_;
  short2 o; o.x = f2bf(v.x * scale); o.y = f2bf(v.y * scale);
  ((short2*)dst)[lane] = o;
}

// ================= PHASE 1: per-chunk local quantities (parallel, 512 blocks)
__global__ __launch_bounds__(256, 2) void chunk_phase1(
    const short* __restrict__ qbf, const short* __restrict__ kbf,
    const float* __restrict__ qkv, const float* __restrict__ gT,
    const float* __restrict__ bT,
    short* __restrict__ Pm, short* __restrict__ GQ, short* __restrict__ KtT,
    short* __restrict__ Wneg, float* __restrict__ Ut, float* __restrict__ Gammac) {
  __shared__ float Al[64 * 64];      // 16 KB
  __shared__ float Gs[64], Gam[64], Dd[64], Bet[64], BG[64];

  int ci = blockIdx.x;
  int c = ci & 15, hv = (ci >> 4) & 15, b = ci >> 8;
  int hk = hv >> 1;
  int t0 = c * CL_;
  int tid = threadIdx.x;
  int wave = tid >> 6, lane = tid & 63, quad = lane >> 4, l16 = lane & 15;

  if (tid < 64) {
    float g = gT[(hv * B_ + b) * T_ + t0 + tid];
    float x = g;
#pragma unroll
    for (int off = 1; off < 64; off <<= 1) {
      float y = __shfl_up(x, off, 64);
      if (tid >= off) x += y;
    }
    Gs[tid] = x;
    float gm = __expf(x);
    Gam[tid] = gm;
    float Gtot = __shfl(x, 63, 64);
    Dd[tid] = __expf(Gtot - x);
    float bb = bT[(hv * B_ + b) * T_ + t0 + tid];
    Bet[tid] = bb;
    BG[tid] = bb * gm;
    if (tid == 63) Gammac[ci] = __expf(x);
  }
  __syncthreads();

  const long kbase = ((long)(b * T_ + t0) * HK_ + hk) * DK_;   // in shorts
  const int kstride = HK_ * DK_;                               // 1024

  // ---- RHS columns into registers (coalesced: lane-consecutive cols) ----
  int half = tid >> 7;        // 0 = V-columns, 1 = betaGammaK-columns
  int col = tid & 127;
  float u[64];
  {
    const float* vcol = qkv + (long)(b * T_ + t0) * CONV_DIM_ + 2 * KEY_DIM_ + hv * DV_ + col;
    const short* kcol = kbf + kbase + col;
    if (half == 0) {
#pragma unroll
      for (int r = 0; r < 64; ++r) u[r] = vcol[(long)r * CONV_DIM_];
    } else {
#pragma unroll
      for (int r = 0; r < 64; ++r) u[r] = bf2f(kcol[(long)r * kstride]);
    }
  }

  // ---- KK^T -> Al (mask s>r, scale beta_s * exp(G_s - G_r)) ----
  {
    f32x4 acc[4] = {};
#pragma unroll
    for (int kk = 0; kk < 4; ++kk) {
      short8 afr = *(const short8*)(kbf + kbase + (long)(16 * wave + l16) * kstride + kk * 32 + quad * 8);
#pragma unroll
      for (int j = 0; j < 4; ++j) {
        short8 bfr = *(const short8*)(kbf + kbase + (long)(16 * j + l16) * kstride + kk * 32 + quad * 8);
        acc[j] = __builtin_amdgcn_mfma_f32_16x16x32_bf16(afr, bfr, acc[j], 0, 0, 0);
      }
    }
#pragma unroll
    for (int j = 0; j < 4; ++j)
#pragma unroll
      for (int r = 0; r < 4; ++r) {
        int row = 16 * wave + quad * 4 + r, colx = 16 * j + l16;
        float v = 0.f;
        if (row > colx) v = Bet[row] * __expf(Gs[row] - Gs[colx]) * acc[j][r];
        Al[row * 64 + colx] = v;
      }
  }
  // ---- QK^T -> Pm (mask t>=s, scale exp(G_t - G_s)) ----
  {
    f32x4 acc[4] = {};
#pragma unroll
    for (int kk = 0; kk < 4; ++kk) {
      short8 afr = *(const short8*)(qbf + kbase + (long)(16 * wave + l16) * kstride + kk * 32 + quad * 8);
#pragma unroll
      for (int j = 0; j < 4; ++j) {
        short8 bfr = *(const short8*)(kbf + kbase + (long)(16 * j + l16) * kstride + kk * 32 + quad * 8);
        acc[j] = __builtin_amdgcn_mfma_f32_16x16x32_bf16(afr, bfr, acc[j], 0, 0, 0);
      }
    }
#pragma unroll
    for (int j = 0; j < 4; ++j)
#pragma unroll
      for (int r = 0; r < 4; ++r) {
        int row = 16 * wave + quad * 4 + r, colx = 16 * j + l16;
        float v = 0.f;
        if (row >= colx) v = __expf(Gs[row] - Gs[colx]) * acc[j][r];
        Pm[(long)ci * 4096 + row * 64 + colx] = f2bf(v);
      }
  }
  // ---- GQ[s][d] = Gam[s]*q[s][d] (coalesced short2 writes) ----
  for (int s = wave; s < 64; s += 4) {
    float gm = Gam[s];
    short2 qv = *(const short2*)(qbf + kbase + (long)s * kstride + lane * 2);
    short2 o;
    o.x = f2bf(bf2f(qv.x) * gm);
    o.y = f2bf(bf2f(qv.y) * gm);
    *(short2*)(GQ + (long)ci * 8192 + s * 128 + lane * 2) = o;
  }
  // ---- KtT[d][s] = k[s][d]*Dd[s] ----
  for (int d = wave; d < 128; d += 4) {
    float kv = bf2f(kbf[kbase + (long)lane * kstride + d]);
    KtT[(long)ci * 8192 + d * 64 + lane] = f2bf(kv * Dd[lane]);
  }
  __syncthreads();   // Al complete

  // ---- scale RHS, register-resident forward substitution ----
  if (half == 0) {
#pragma unroll
    for (int r = 0; r < 64; ++r) u[r] *= Bet[r];
  } else {
#pragma unroll
    for (int r = 0; r < 64; ++r) u[r] *= BG[r];
  }
#pragma unroll
  for (int s = 1; s < 64; ++s) {
    const float* Ar = Al + s * 64;
    float acc = 0.f;
#pragma unroll
    for (int r4 = 0; r4 + 4 <= s; r4 += 4) {
      float4 a = *(const float4*)(Ar + r4);
      acc += (a.x * u[r4] + a.y * u[r4 + 1]) + (a.z * u[r4 + 2] + a.w * u[r4 + 3]);
    }
#pragma unroll
    for (int r = (s / 4) * 4; r < s; ++r) acc += Ar[r] * u[r];
    u[s] -= acc;
  }
  // ---- write out (coalesced) ----
  if (half == 0) {
    float* up = Ut + (long)ci * 8192 + col;
#pragma unroll
    for (int s = 0; s < 64; ++s) up[s * 128] = u[s];
  } else {
    short* wp = Wneg + (long)ci * 8192 + col;
#pragma unroll
    for (int s = 0; s < 64; ++s) wp[s * 128] = f2bf(-u[s]);
  }
}

// ================= PHASE 2: state recurrence over chunks (256 blocks) ========
__global__ __launch_bounds__(256) void chunk_phase2(
    const short* __restrict__ Wneg, const float* __restrict__ Ut,
    const short* __restrict__ KtT, const float* __restrict__ Gammac,
    short* __restrict__ UTg, short* __restrict__ ScTg) {
  __shared__ short SLT[16 * 136];   // S^T slice [n 16][m 128 pad 136]
  __shared__ short ULT[16 * 72];    // U'^T slice [n 16][s 64 pad 72]
  int bi = blockIdx.x >> 3;          // b*16+hv
  int n0 = (blockIdx.x & 7) * 16;    // col-slice base
  int tid = threadIdx.x, wave = tid >> 6, lane = tid & 63, quad = lane >> 4, l16 = lane & 15;
  f32x4 S2[2] = {};   // rows 32*wave+16i+quad*4+r, col n0+l16

  long ci0 = (long)bi * NCH_;
  // preload chunk-0 operands
  short8 Wr[4]; f32x4 Ur; short8 Kr[2][2];
  {
    long ci = ci0;
#pragma unroll
    for (int kk = 0; kk < 4; ++kk)
      Wr[kk] = *(const short8*)(Wneg + ci * 8192 + (16 * wave + l16) * 128 + kk * 32 + quad * 8);
    const float* up = Ut + ci * 8192 + (16 * wave + quad * 4) * 128 + n0 + l16;
#pragma unroll
    for (int r = 0; r < 4; ++r) Ur[r] = up[r * 128];
#pragma unroll
    for (int kk = 0; kk < 2; ++kk)
#pragma unroll
      for (int i = 0; i < 2; ++i)
        Kr[kk][i] = *(const short8*)(KtT + ci * 8192 + (32 * wave + 16 * i + l16) * 64 + kk * 32 + quad * 8);
  }

  for (int ch = 0; ch < NCH_; ++ch) {
    long ci = ci0 + ch;
    // 1. write S^T slice to LDS + global
#pragma unroll
    for (int i = 0; i < 2; ++i) {
      int m0 = 32 * wave + 16 * i + quad * 4;
      short4 p;
      p.x = f2bf(S2[i][0]); p.y = f2bf(S2[i][1]);
      p.z = f2bf(S2[i][2]); p.w = f2bf(S2[i][3]);
      *(short4*)(SLT + l16 * 136 + m0) = p;
      *(short4*)(ScTg + ci * 16384 + (n0 + l16) * 128 + m0) = p;
    }
    // prefetch next-chunk operands into registers (overlaps barriers + MFMA)
    short8 Wn[4]; f32x4 Un; short8 Kn[2][2];
    if (ch + 1 < NCH_) {
      long cj = ci + 1;
#pragma unroll
      for (int kk = 0; kk < 4; ++kk)
        Wn[kk] = *(const short8*)(Wneg + cj * 8192 + (16 * wave + l16) * 128 + kk * 32 + quad * 8);
      const float* up = Ut + cj * 8192 + (16 * wave + quad * 4) * 128 + n0 + l16;
#pragma unroll
      for (int r = 0; r < 4; ++r) Un[r] = up[r * 128];
#pragma unroll
      for (int kk = 0; kk < 2; ++kk)
#pragma unroll
        for (int i = 0; i < 2; ++i)
          Kn[kk][i] = *(const short8*)(KtT + cj * 8192 + (32 * wave + 16 * i + l16) * 64 + kk * 32 + quad * 8);
    }
    __syncthreads();
    // 2. U' = U - W @ S^T  (contraction over m=128)
    f32x4 Ua = Ur;
#pragma unroll
    for (int kk = 0; kk < 4; ++kk) {
      short8 bfv = *(const short8*)(SLT + l16 * 136 + kk * 32 + quad * 8);
      Ua = __builtin_amdgcn_mfma_f32_16x16x32_bf16(Wr[kk], bfv, Ua, 0, 0, 0);
    }
    {
      int s0 = 16 * wave + quad * 4;
      short4 p;
      p.x = f2bf(Ua[0]); p.y = f2bf(Ua[1]); p.z = f2bf(Ua[2]); p.w = f2bf(Ua[3]);
      *(short4*)(ULT + l16 * 72 + s0) = p;
      *(short4*)(UTg + ci * 8192 + (n0 + l16) * 64 + s0) = p;
    }
    __syncthreads();
    // 3. S = S*gamma + KtT @ U'^T  (contraction over s=64)
    float gc = Gammac[ci];
#pragma unroll
    for (int i = 0; i < 2; ++i)
#pragma unroll
      for (int r = 0; r < 4; ++r) S2[i][r] *= gc;
#pragma unroll
    for (int kk = 0; kk < 2; ++kk) {
      short8 bfv = *(const short8*)(ULT + l16 * 72 + kk * 32 + quad * 8);
#pragma unroll
      for (int i = 0; i < 2; ++i)
        S2[i] = __builtin_amdgcn_mfma_f32_16x16x32_bf16(Kr[kk][i], bfv, S2[i], 0, 0, 0);
    }
    __syncthreads();
    if (ch + 1 < NCH_) {
#pragma unroll
      for (int kk = 0; kk < 4; ++kk) Wr[kk] = Wn[kk];
      Ur = Un;
#pragma unroll
      for (int kk = 0; kk < 2; ++kk)
#pragma unroll
        for (int i = 0; i < 2; ++i) Kr[kk][i] = Kn[kk][i];
    }
  }
}

// ================= PHASE 3: outputs + fused gated RMSNorm (512 blocks) =======
__global__ __launch_bounds__(256) void chunk_phase3(
    const short* __restrict__ GQ, const short* __restrict__ ScTg,
    const short* __restrict__ Pm, const short* __restrict__ UTg,
    const float* __restrict__ zbuf, const float* __restrict__ nw,
    short* __restrict__ obf) {
  int ci = blockIdx.x;
  int c = ci & 15, hv = (ci >> 4) & 15, b = ci >> 8;
  int t0 = c * CL_;
  int tid = threadIdx.x, wave = tid >> 6, lane = tid & 63, quad = lane >> 4, l16 = lane & 15;
  f32x4 acc[8] = {};
#pragma unroll
  for (int kk = 0; kk < 4; ++kk) {
    short8 af = *(const short8*)(GQ + (long)ci * 8192 + (16 * wave + l16) * 128 + kk * 32 + quad * 8);
#pragma unroll
    for (int j = 0; j < 8; ++j) {
      short8 bfv = *(const short8*)(ScTg + (long)ci * 16384 + (16 * j + l16) * 128 + kk * 32 + quad * 8);
      acc[j] = __builtin_amdgcn_mfma_f32_16x16x32_bf16(af, bfv, acc[j], 0, 0, 0);
    }
  }
#pragma unroll
  for (int kk = 0; kk < 2; ++kk) {
    short8 af = *(const short8*)(Pm + (long)ci * 4096 + (16 * wave + l16) * 64 + kk * 32 + quad * 8);
#pragma unroll
    for (int j = 0; j < 8; ++j) {
      short8 bfv = *(const short8*)(UTg + (long)ci * 8192 + (16 * j + l16) * 64 + kk * 32 + quad * 8);
      acc[j] = __builtin_amdgcn_mfma_f32_16x16x32_bf16(af, bfv, acc[j], 0, 0, 0);
    }
  }
  // fused gated RMSNorm * silu(z) epilogue.
#pragma unroll
  for (int r = 0; r < 4; ++r) {
    float ss = 0.f;
#pragma unroll
    for (int j = 0; j < 8; ++j) ss += acc[j][r] * acc[j][r];
    ss += __shfl_xor(ss, 1, 64);
    ss += __shfl_xor(ss, 2, 64);
    ss += __shfl_xor(ss, 4, 64);
    ss += __shfl_xor(ss, 8, 64);
    float scale = rsqrtf(ss * (1.f / 128.f) + 1e-6f);
    int t = t0 + 16 * wave + quad * 4 + r;
    long base = (long)(b * T_ + t) * VALUE_DIM_ + hv * DV_;
#pragma unroll
    for (int j = 0; j < 8; ++j) {
      int n = 16 * j + l16;
      float zv = zbuf[base + n];
      float sz = zv * (1.f / (1.f + __expf(-zv)));
      obf[base + n] = f2bf(acc[j][r] * scale * nw[n] * sz);
    }
  }
}

// ---------------- launcher ----------------
extern "C" void kernel_launch(void* const* d_in, const int* in_sizes, int n_in,
                              void* d_out, int out_size, void* d_ws, size_t ws_size,
                              hipStream_t stream) {
  const float* hidden  = (const float*)d_in[0];
  const float* W_qkv   = (const float*)d_in[1];
  const float* W_z     = (const float*)d_in[2];
  const float* W_b     = (const float*)d_in[3];
  const float* W_a     = (const float*)d_in[4];
  const float* conv_w  = (const float*)d_in[5];
  const float* dt_bias = (const float*)d_in[6];
  const float* A_log   = (const float*)d_in[7];
  const float* norm_w  = (const float*)d_in[8];
  const float* W_out   = (const float*)d_in[9];
  float* out = (float*)d_out;

  char* ws = (char*)d_ws;
  size_t off = 0;
  auto alloc = [&](size_t bytes) {
    void* p = ws + off;
    off += (bytes + 255) & ~(size_t)255;
    return p;
  };
  short* hidden_bf = (short*)alloc((size_t)BT_ * D_ * 2);           // 8 MB
  short* WcatT     = (short*)alloc((size_t)(CONV_DIM_ + VALUE_DIM_) * D_ * 2); // 24 MB
  short* WoutT     = (short*)alloc((size_t)D_ * VALUE_DIM_ * 2);    // 8 MB
  float* mixed     = (float*)alloc((size_t)BT_ * CONV_DIM_ * 4);    // 32 MB
  float* qkv       = (float*)alloc((size_t)BT_ * CONV_DIM_ * 4);    // 32 MB
  float* zbuf      = (float*)alloc((size_t)BT_ * VALUE_DIM_ * 4);   // 16 MB
  short* qbf       = (short*)alloc((size_t)BT_ * KEY_DIM_ * 2);     // 4 MB
  short* kbf       = (short*)alloc((size_t)BT_ * KEY_DIM_ * 2);     // 4 MB
  float* betab     = (float*)alloc((size_t)BT_ * HV_ * 4);
  float* gb        = (float*)alloc((size_t)BT_ * HV_ * 4);
  float* Wba32     = (float*)alloc((size_t)D_ * 32 * 4);            // 256 KB
  short* Wneg      = (short*)alloc((size_t)512 * 8192 * 2);         // 8 MB
  float* Ut32      = (float*)alloc((size_t)512 * 8192 * 4);         // 16 MB
  short* KtT       = (short*)alloc((size_t)512 * 8192 * 2);         // 8 MB
  short* UTg       = (short*)alloc((size_t)512 * 8192 * 2);         // 8 MB
  short* ScTg      = (short*)alloc((size_t)512 * 16384 * 2);        // 16 MB
  float* Gammac    = (float*)alloc((size_t)512 * 4);
  // aliases (into buffers dead by the time they're written):
  short* Pm   = (short*)(mixed + (size_t)BT_ * VALUE_DIM_);         // 4 MB (mixed dead after conv)
  short* GQ   = Pm + (size_t)512 * 4096;                            // 8 MB
  short* obf  = hidden_bf;          // dead after fused qkv+z GEMM
  float* Cpart = qkv;               // 32 MB; qkv dead after phase1 (split-K partials)

  dim3 tb32(32, 8);
  transpose_cast<<<dim3(CONV_DIM_ / 32, D_ / 32), tb32, 0, stream>>>(W_qkv, WcatT, D_, CONV_DIM_);
  transpose_cast<<<dim3(VALUE_DIM_ / 32, D_ / 32), tb32, 0, stream>>>(W_z, WcatT + (size_t)CONV_DIM_ * D_, D_, VALUE_DIM_);
  transpose_cast<<<dim3(D_ / 32, VALUE_DIM_ / 32), tb32, 0, stream>>>(W_out, WoutT, VALUE_DIM_, D_);
  interleave_ba<<<32 * D_ / 256, 256, 0, stream>>>(W_b, W_a, Wba32);

  // beta/g projections + fused hidden bf16 cast (must precede the GEMM)
  small_proj<<<BT_ / 2, 256, 0, stream>>>(hidden, Wba32, dt_bias, A_log, betab, gb, hidden_bf);

  // fused qkv + z projection: 256x192 8-phase, grid 32x8 = 256 blocks (1/CU)
  gemm256n192<<<dim3((CONV_DIM_ + VALUE_DIM_) / 192, BT_ / 256), 512, 0, stream>>>(
      hidden_bf, WcatT, mixed, zbuf, CONV_DIM_, VALUE_DIM_, D_);
  conv_silu<<<BT_ * CONV_DIM_ / 256, 256, 0, stream>>>(mixed, conv_w, qkv);
  qknorm<<<BT_ * HK_ * 2, 64, 0, stream>>>(qkv, qbf, kbf);

  chunk_phase1<<<512, 256, 0, stream>>>(qbf, kbf, qkv, gb, betab, Pm, GQ, KtT, Wneg, Ut32, Gammac);
  chunk_phase2<<<256, 256, 0, stream>>>(Wneg, Ut32, KtT, Gammac, UTg, ScTg);
  chunk_phase3<<<512, 256, 0, stream>>>(GQ, ScTg, Pm, UTg, zbuf, norm_w, obf);

  // out projection: 256x128 8-phase split-K=2 -> 256 blocks, then partial-sum
  gemm256ks<<<dim3(D_ / 128, BT_ / 256, 2), 512, 0, stream>>>(obf, WoutT, Cpart, BT_, D_, VALUE_DIM_);
  add2<<<(BT_ * D_ / 4 + 255) / 256, 256, 0, stream>>>(Cpart, Cpart + (size_t)BT_ * D_, out, BT_ * D_ / 4);
}

// Round 5
// 364.841 us; speedup vs baseline: 1.0393x; 1.0002x over previous
//
#include <hip/hip_runtime.h>
#include <hip/hip_bf16.h>

// GatedDeltaNet: B=2, T=1024, D=2048, HK=8, HV=16, DK=DV=128, KW=4
#define B_ 2
#define T_ 1024
#define D_ 2048
#define HK_ 8
#define HV_ 16
#define DK_ 128
#define DV_ 128
#define KEY_DIM_ 1024
#define VALUE_DIM_ 2048
#define CONV_DIM_ 4096
#define BT_ 2048   // B*T
#define NCH_ 16    // chunks per sequence (T/64)
#define CL_ 64     // chunk length

typedef __attribute__((ext_vector_type(8))) short short8;
typedef __attribute__((ext_vector_type(4))) float f32x4;

__device__ __forceinline__ short f2bf(float x) {
  __hip_bfloat16 h = __float2bfloat16(x);
  return *reinterpret_cast<short*>(&h);
}
__device__ __forceinline__ float bf2f(short u) {
  unsigned int x = ((unsigned int)(unsigned short)u) << 16;
  return __int_as_float(x);
}

#define GLOAD_LDS16(g, l)                                             \
  __builtin_amdgcn_global_load_lds(                                   \
      (const __attribute__((address_space(1))) void*)(g),             \
      (__attribute__((address_space(3))) void*)(l), 16, 0, 0)

// ---------------- transpose + cast: W[R,C] f32 -> WT[C,R] bf16 ----------------
__global__ void transpose_cast(const float* __restrict__ W, short* __restrict__ WT, int R, int C) {
  __shared__ float tile[32][33];
  int tx = threadIdx.x, ty = threadIdx.y;
  int x = blockIdx.x * 32 + tx;
#pragma unroll
  for (int j = 0; j < 4; ++j) {
    int r = blockIdx.y * 32 + ty + j * 8;
    tile[ty + j * 8][tx] = W[(long)r * C + x];
  }
  __syncthreads();
  int ro = blockIdx.y * 32 + tx;
#pragma unroll
  for (int j = 0; j < 4; ++j) {
    int co = blockIdx.x * 32 + ty + j * 8;
    WT[(long)co * R + ro] = f2bf(tile[tx][ty + j * 8]);
  }
}

// ---------------- W_b|W_a -> Wba32[k][32] (k-major interleave) ----------------
__global__ void interleave_ba(const float* __restrict__ Wb, const float* __restrict__ Wa,
                              float* __restrict__ Wba32) {
  int i = blockIdx.x * 256 + threadIdx.x;   // D*32
  int c = i & 31, k = i >> 5;
  Wba32[i] = (c < 16) ? Wb[k * 16 + c] : Wa[k * 16 + (c - 16)];
}

#define MFMA_(d, x, y) d = __builtin_amdgcn_mfma_f32_16x16x32_bf16(x, y, d, 0, 0, 0)
#define BAR_() do { __builtin_amdgcn_s_barrier(); __builtin_amdgcn_sched_barrier(0); } while (0)
#define PRIO_ON_() __builtin_amdgcn_s_setprio(1)
#define PRIO_OFF_() do { __builtin_amdgcn_s_setprio(0); __builtin_amdgcn_sched_barrier(0); } while (0)

// ========== 256x192 8-phase GEMM (grid 32x8 = 256 blocks = 1/CU) ============
__global__ __launch_bounds__(512) void gemm256n192(const short* __restrict__ A,
                                                   const short* __restrict__ Bt,
                                                   float* __restrict__ C0,
                                                   float* __restrict__ C1,
                                                   int N0, int N1, int K) {
  __shared__ short lds[57344];   // 2 bufs x 28672 shorts (A 16384 | B 12288)
  const int tid = threadIdx.x;
  const int lane = tid & 63, wid = tid >> 6;
  const int quad = lane >> 4, l16 = lane & 15;
  const int wm = (wid >> 1) * 64, wn = (wid & 1) * 96;
  const int m0 = blockIdx.y * 256, n0 = blockIdx.x * 192;

  const int r8 = tid >> 3, t8 = (tid & 7) * 8;
  const int csw = t8 ^ ((r8 & 7) << 3);
  const int cswr = (quad ^ (l16 & 7)) << 3;
  const int NIT = K >> 7;   // 2 K-tiles per iteration

  f32x4 acc[4][6] = {};
  short8 a[4][2], bl[3][2], bh[3][2];

#define SGA(p, kt, rb) GLOAD_LDS16(A + (long)(m0 + (rb) + r8) * K + (kt) * 64 + csw, \
                                   lds + (p) * 28672 + ((rb) + r8) * 64 + t8)
#define SGB(p, kt, rb) GLOAD_LDS16(Bt + (long)(n0 + (rb) + r8) * K + (kt) * 64 + csw, \
                                   lds + (p) * 28672 + 16384 + ((rb) + r8) * 64 + t8)
#define RDA(p, r, kk) (*(const short8*)(lds + (p) * 28672 + (r) * 64 + (cswr ^ ((kk) << 5))))
#define RDB(p, r, kk) (*(const short8*)(lds + (p) * 28672 + 16384 + (r) * 64 + (cswr ^ ((kk) << 5))))

  // prologue: tile0 full (7), tile1 minus last B unit (6) -> 13 outstanding
  SGA(0, 0, 0); SGA(0, 0, 64); SGA(0, 0, 128); SGA(0, 0, 192);
  SGB(0, 0, 0); SGB(0, 0, 64); SGB(0, 0, 128);
  SGA(1, 1, 0); SGA(1, 1, 64); SGA(1, 1, 128); SGA(1, 1, 192);
  SGB(1, 1, 0); SGB(1, 1, 64);
  asm volatile("s_waitcnt vmcnt(6)" ::: "memory");
  BAR_();

#pragma unroll 1
  for (int i = 0; i < NIT; ++i) {
    const int tb = 2 * i + 1, tc = 2 * i + 2, td = 2 * i + 3;
    const bool more = (i + 1 < NIT);

    // ---- ph1: buf0, m01 x n-lo ----
#pragma unroll
    for (int mi = 0; mi < 2; ++mi) {
      a[mi][0] = RDA(0, wm + mi * 16 + l16, 0);
      a[mi][1] = RDA(0, wm + mi * 16 + l16, 1);
    }
#pragma unroll
    for (int ni = 0; ni < 3; ++ni) {
      bl[ni][0] = RDB(0, wn + ni * 16 + l16, 0);
      bl[ni][1] = RDB(0, wn + ni * 16 + l16, 1);
    }
    SGB(1, tb, 128);           // deferred last B unit of tile tb (buf1)
    BAR_();
    PRIO_ON_();
#pragma unroll
    for (int mi = 0; mi < 2; ++mi)
#pragma unroll
      for (int ni = 0; ni < 3; ++ni) {
        MFMA_(acc[mi][ni], a[mi][0], bl[ni][0]);
        MFMA_(acc[mi][ni], a[mi][1], bl[ni][1]);
      }
    PRIO_OFF_();
    __builtin_amdgcn_s_barrier();

    // ---- ph2: buf0, m23 x n-lo ----
    __builtin_amdgcn_sched_barrier(0);
#pragma unroll
    for (int mi = 2; mi < 4; ++mi) {
      a[mi][0] = RDA(0, wm + mi * 16 + l16, 0);
      a[mi][1] = RDA(0, wm + mi * 16 + l16, 1);
    }
    BAR_();
    PRIO_ON_();
#pragma unroll
    for (int mi = 2; mi < 4; ++mi)
#pragma unroll
      for (int ni = 0; ni < 3; ++ni) {
        MFMA_(acc[mi][ni], a[mi][0], bl[ni][0]);
        MFMA_(acc[mi][ni], a[mi][1], bl[ni][1]);
      }
    PRIO_OFF_();
    __builtin_amdgcn_s_barrier();

    // ---- ph3: buf0, m01 x n-hi ----
    __builtin_amdgcn_sched_barrier(0);
#pragma unroll
    for (int ni = 0; ni < 3; ++ni) {
      bh[ni][0] = RDB(0, wn + 48 + ni * 16 + l16, 0);
      bh[ni][1] = RDB(0, wn + 48 + ni * 16 + l16, 1);
    }
    if (more) { SGA(0, tc, 0); SGA(0, tc, 64); }
    BAR_();
    PRIO_ON_();
#pragma unroll
    for (int mi = 0; mi < 2; ++mi)
#pragma unroll
      for (int ni = 0; ni < 3; ++ni) {
        MFMA_(acc[mi][3 + ni], a[mi][0], bh[ni][0]);
        MFMA_(acc[mi][3 + ni], a[mi][1], bh[ni][1]);
      }
    PRIO_OFF_();
    __builtin_amdgcn_s_barrier();

    // ---- ph4: buf0, m23 x n-hi ----
    __builtin_amdgcn_sched_barrier(0);
    if (more) { SGA(0, tc, 128); SGA(0, tc, 192); SGB(0, tc, 0); SGB(0, tc, 64); }
    BAR_();
    PRIO_ON_();
#pragma unroll
    for (int mi = 2; mi < 4; ++mi)
#pragma unroll
      for (int ni = 0; ni < 3; ++ni) {
        MFMA_(acc[mi][3 + ni], a[mi][0], bh[ni][0]);
        MFMA_(acc[mi][3 + ni], a[mi][1], bh[ni][1]);
      }
    PRIO_OFF_();
    if (more) { asm volatile("s_waitcnt vmcnt(6)" ::: "memory"); }
    else      { asm volatile("s_waitcnt vmcnt(0)" ::: "memory"); }
    __builtin_amdgcn_s_barrier();

    // ---- ph5: buf1, m01 x n-lo ----
    __builtin_amdgcn_sched_barrier(0);
#pragma unroll
    for (int mi = 0; mi < 2; ++mi) {
      a[mi][0] = RDA(1, wm + mi * 16 + l16, 0);
      a[mi][1] = RDA(1, wm + mi * 16 + l16, 1);
    }
#pragma unroll
    for (int ni = 0; ni < 3; ++ni) {
      bl[ni][0] = RDB(1, wn + ni * 16 + l16, 0);
      bl[ni][1] = RDB(1, wn + ni * 16 + l16, 1);
    }
    if (more) SGB(0, tc, 128);
    BAR_();
    PRIO_ON_();
#pragma unroll
    for (int mi = 0; mi < 2; ++mi)
#pragma unroll
      for (int ni = 0; ni < 3; ++ni) {
        MFMA_(acc[mi][ni], a[mi][0], bl[ni][0]);
        MFMA_(acc[mi][ni], a[mi][1], bl[ni][1]);
      }
    PRIO_OFF_();
    __builtin_amdgcn_s_barrier();

    // ---- ph6: buf1, m23 x n-lo ----
    __builtin_amdgcn_sched_barrier(0);
#pragma unroll
    for (int mi = 2; mi < 4; ++mi) {
      a[mi][0] = RDA(1, wm + mi * 16 + l16, 0);
      a[mi][1] = RDA(1, wm + mi * 16 + l16, 1);
    }
    BAR_();
    PRIO_ON_();
#pragma unroll
    for (int mi = 2; mi < 4; ++mi)
#pragma unroll
      for (int ni = 0; ni < 3; ++ni) {
        MFMA_(acc[mi][ni], a[mi][0], bl[ni][0]);
        MFMA_(acc[mi][ni], a[mi][1], bl[ni][1]);
      }
    PRIO_OFF_();
    __builtin_amdgcn_s_barrier();

    // ---- ph7: buf1, m01 x n-hi ----
    __builtin_amdgcn_sched_barrier(0);
#pragma unroll
    for (int ni = 0; ni < 3; ++ni) {
      bh[ni][0] = RDB(1, wn + 48 + ni * 16 + l16, 0);
      bh[ni][1] = RDB(1, wn + 48 + ni * 16 + l16, 1);
    }
    if (more) { SGA(1, td, 0); SGA(1, td, 64); }
    BAR_();
    PRIO_ON_();
#pragma unroll
    for (int mi = 0; mi < 2; ++mi)
#pragma unroll
      for (int ni = 0; ni < 3; ++ni) {
        MFMA_(acc[mi][3 + ni], a[mi][0], bh[ni][0]);
        MFMA_(acc[mi][3 + ni], a[mi][1], bh[ni][1]);
      }
    PRIO_OFF_();
    __builtin_amdgcn_s_barrier();

    // ---- ph8: buf1, m23 x n-hi ----
    __builtin_amdgcn_sched_barrier(0);
    if (more) { SGA(1, td, 128); SGA(1, td, 192); SGB(1, td, 0); SGB(1, td, 64); }
    BAR_();
    PRIO_ON_();
#pragma unroll
    for (int mi = 2; mi < 4; ++mi)
#pragma unroll
      for (int ni = 0; ni < 3; ++ni) {
        MFMA_(acc[mi][3 + ni], a[mi][0], bh[ni][0]);
        MFMA_(acc[mi][3 + ni], a[mi][1], bh[ni][1]);
      }
    PRIO_OFF_();
    if (more) { asm volatile("s_waitcnt vmcnt(6)" ::: "memory"); }
    else      { asm volatile("s_waitcnt vmcnt(0)" ::: "memory"); }
    __builtin_amdgcn_s_barrier();
    __builtin_amdgcn_sched_barrier(0);
  }

#pragma unroll
  for (int mi = 0; mi < 4; ++mi)
#pragma unroll
    for (int ni = 0; ni < 6; ++ni)
#pragma unroll
      for (int r = 0; r < 4; ++r) {
        int row = m0 + wm + mi * 16 + quad * 4 + r;
        int col = n0 + wn + ni * 16 + l16;
        if (col < N0) C0[(long)row * N0 + col] = acc[mi][ni][r];
        else          C1[(long)row * N1 + (col - N0)] = acc[mi][ni][r];
      }
#undef SGA
#undef SGB
#undef RDA
#undef RDB
}

// ========== 256x128 8-phase GEMM, split-K=2 (grid 16x8x2 = 256 blocks) ======
__global__ __launch_bounds__(512) void gemm256ks(const short* __restrict__ Ag,
                                                 const short* __restrict__ Btg,
                                                 float* __restrict__ Cp,
                                                 int M, int N, int K) {
  __shared__ short lds[49152];   // 2 bufs x 24576 shorts (A 16384 | B 8192)
  const int tid = threadIdx.x;
  const int lane = tid & 63, wid = tid >> 6;
  const int quad = lane >> 4, l16 = lane & 15;
  const int wm = (wid >> 1) * 64, wn = (wid & 1) * 64;
  const int m0 = blockIdx.y * 256, n0 = blockIdx.x * 128;
  const int kh = K >> 1;
  const short* A = Ag + blockIdx.z * kh;    // column offset into K
  const short* Bt = Btg + blockIdx.z * kh;

  const int r8 = tid >> 3, t8 = (tid & 7) * 8;
  const int csw = t8 ^ ((r8 & 7) << 3);
  const int cswr = (quad ^ (l16 & 7)) << 3;
  const int NIT = kh >> 7;

  f32x4 acc[4][4] = {};
  short8 a[4][2], bl[2][2], bh[2][2];

#define SGA(p, kt, rb) GLOAD_LDS16(A + (long)(m0 + (rb) + r8) * K + (kt) * 64 + csw, \
                                   lds + (p) * 24576 + ((rb) + r8) * 64 + t8)
#define SGB(p, kt, rb) GLOAD_LDS16(Bt + (long)(n0 + (rb) + r8) * K + (kt) * 64 + csw, \
                                   lds + (p) * 24576 + 16384 + ((rb) + r8) * 64 + t8)
#define RDA(p, r, kk) (*(const short8*)(lds + (p) * 24576 + (r) * 64 + (cswr ^ ((kk) << 5))))
#define RDB(p, r, kk) (*(const short8*)(lds + (p) * 24576 + 16384 + (r) * 64 + (cswr ^ ((kk) << 5))))

  // prologue: tile0 full (6), tile1 minus last B unit (5) -> 11 outstanding
  SGA(0, 0, 0); SGA(0, 0, 64); SGA(0, 0, 128); SGA(0, 0, 192);
  SGB(0, 0, 0); SGB(0, 0, 64);
  SGA(1, 1, 0); SGA(1, 1, 64); SGA(1, 1, 128); SGA(1, 1, 192);
  SGB(1, 1, 0);
  asm volatile("s_waitcnt vmcnt(5)" ::: "memory");
  BAR_();

#pragma unroll 1
  for (int i = 0; i < NIT; ++i) {
    const int tb = 2 * i + 1, tc = 2 * i + 2, td = 2 * i + 3;
    const bool more = (i + 1 < NIT);

    // ---- ph1 ----
#pragma unroll
    for (int mi = 0; mi < 2; ++mi) {
      a[mi][0] = RDA(0, wm + mi * 16 + l16, 0);
      a[mi][1] = RDA(0, wm + mi * 16 + l16, 1);
    }
#pragma unroll
    for (int ni = 0; ni < 2; ++ni) {
      bl[ni][0] = RDB(0, wn + ni * 16 + l16, 0);
      bl[ni][1] = RDB(0, wn + ni * 16 + l16, 1);
    }
    SGB(1, tb, 64);
    BAR_();
    PRIO_ON_();
#pragma unroll
    for (int mi = 0; mi < 2; ++mi)
#pragma unroll
      for (int ni = 0; ni < 2; ++ni) {
        MFMA_(acc[mi][ni], a[mi][0], bl[ni][0]);
        MFMA_(acc[mi][ni], a[mi][1], bl[ni][1]);
      }
    PRIO_OFF_();
    __builtin_amdgcn_s_barrier();

    // ---- ph2 ----
    __builtin_amdgcn_sched_barrier(0);
#pragma unroll
    for (int mi = 2; mi < 4; ++mi) {
      a[mi][0] = RDA(0, wm + mi * 16 + l16, 0);
      a[mi][1] = RDA(0, wm + mi * 16 + l16, 1);
    }
    BAR_();
    PRIO_ON_();
#pragma unroll
    for (int mi = 2; mi < 4; ++mi)
#pragma unroll
      for (int ni = 0; ni < 2; ++ni) {
        MFMA_(acc[mi][ni], a[mi][0], bl[ni][0]);
        MFMA_(acc[mi][ni], a[mi][1], bl[ni][1]);
      }
    PRIO_OFF_();
    __builtin_amdgcn_s_barrier();

    // ---- ph3 ----
    __builtin_amdgcn_sched_barrier(0);
#pragma unroll
    for (int ni = 0; ni < 2; ++ni) {
      bh[ni][0] = RDB(0, wn + 32 + ni * 16 + l16, 0);
      bh[ni][1] = RDB(0, wn + 32 + ni * 16 + l16, 1);
    }
    if (more) { SGA(0, tc, 0); SGA(0, tc, 64); }
    BAR_();
    PRIO_ON_();
#pragma unroll
    for (int mi = 0; mi < 2; ++mi)
#pragma unroll
      for (int ni = 0; ni < 2; ++ni) {
        MFMA_(acc[mi][2 + ni], a[mi][0], bh[ni][0]);
        MFMA_(acc[mi][2 + ni], a[mi][1], bh[ni][1]);
      }
    PRIO_OFF_();
    __builtin_amdgcn_s_barrier();

    // ---- ph4 ----
    __builtin_amdgcn_sched_barrier(0);
    if (more) { SGA(0, tc, 128); SGA(0, tc, 192); SGB(0, tc, 0); }
    BAR_();
    PRIO_ON_();
#pragma unroll
    for (int mi = 2; mi < 4; ++mi)
#pragma unroll
      for (int ni = 0; ni < 2; ++ni) {
        MFMA_(acc[mi][2 + ni], a[mi][0], bh[ni][0]);
        MFMA_(acc[mi][2 + ni], a[mi][1], bh[ni][1]);
      }
    PRIO_OFF_();
    if (more) { asm volatile("s_waitcnt vmcnt(5)" ::: "memory"); }
    else      { asm volatile("s_waitcnt vmcnt(0)" ::: "memory"); }
    __builtin_amdgcn_s_barrier();

    // ---- ph5 ----
    __builtin_amdgcn_sched_barrier(0);
#pragma unroll
    for (int mi = 0; mi < 2; ++mi) {
      a[mi][0] = RDA(1, wm + mi * 16 + l16, 0);
      a[mi][1] = RDA(1, wm + mi * 16 + l16, 1);
    }
#pragma unroll
    for (int ni = 0; ni < 2; ++ni) {
      bl[ni][0] = RDB(1, wn + ni * 16 + l16, 0);
      bl[ni][1] = RDB(1, wn + ni * 16 + l16, 1);
    }
    if (more) SGB(0, tc, 64);
    BAR_();
    PRIO_ON_();
#pragma unroll
    for (int mi = 0; mi < 2; ++mi)
#pragma unroll
      for (int ni = 0; ni < 2; ++ni) {
        MFMA_(acc[mi][ni], a[mi][0], bl[ni][0]);
        MFMA_(acc[mi][ni], a[mi][1], bl[ni][1]);
      }
    PRIO_OFF_();
    __builtin_amdgcn_s_barrier();

    // ---- ph6 ----
    __builtin_amdgcn_sched_barrier(0);
#pragma unroll
    for (int mi = 2; mi < 4; ++mi) {
      a[mi][0] = RDA(1, wm + mi * 16 + l16, 0);
      a[mi][1] = RDA(1, wm + mi * 16 + l16, 1);
    }
    BAR_();
    PRIO_ON_();
#pragma unroll
    for (int mi = 2; mi < 4; ++mi)
#pragma unroll
      for (int ni = 0; ni < 2; ++ni) {
        MFMA_(acc[mi][ni], a[mi][0], bl[ni][0]);
        MFMA_(acc[mi][ni], a[mi][1], bl[ni][1]);
      }
    PRIO_OFF_();
    __builtin_amdgcn_s_barrier();

    // ---- ph7 ----
    __builtin_amdgcn_sched_barrier(0);
#pragma unroll
    for (int ni = 0; ni < 2; ++ni) {
      bh[ni][0] = RDB(1, wn + 32 + ni * 16 + l16, 0);
      bh[ni][1] = RDB(1, wn + 32 + ni * 16 + l16, 1);
    }
    if (more) { SGA(1, td, 0); SGA(1, td, 64); }
    BAR_();
    PRIO_ON_();
#pragma unroll
    for (int mi = 0; mi < 2; ++mi)
#pragma unroll
      for (int ni = 0; ni < 2; ++ni) {
        MFMA_(acc[mi][2 + ni], a[mi][0], bh[ni][0]);
        MFMA_(acc[mi][2 + ni], a[mi][1], bh[ni][1]);
      }
    PRIO_OFF_();
    __builtin_amdgcn_s_barrier();

    // ---- ph8 ----
    __builtin_amdgcn_sched_barrier(0);
    if (more) { SGA(1, td, 128); SGA(1, td, 192); SGB(1, td, 0); }
    BAR_();
    PRIO_ON_();
#pragma unroll
    for (int mi = 2; mi < 4; ++mi)
#pragma unroll
      for (int ni = 0; ni < 2; ++ni) {
        MFMA_(acc[mi][2 + ni], a[mi][0], bh[ni][0]);
        MFMA_(acc[mi][2 + ni], a[mi][1], bh[ni][1]);
      }
    PRIO_OFF_();
    if (more) { asm volatile("s_waitcnt vmcnt(5)" ::: "memory"); }
    else      { asm volatile("s_waitcnt vmcnt(0)" ::: "memory"); }
    __builtin_amdgcn_s_barrier();
    __builtin_amdgcn_sched_barrier(0);
  }

  float* Cz = Cp + (long)blockIdx.z * M * N;
#pragma unroll
  for (int mi = 0; mi < 4; ++mi)
#pragma unroll
    for (int ni = 0; ni < 4; ++ni)
#pragma unroll
      for (int r = 0; r < 4; ++r) {
        int row = m0 + wm + mi * 16 + quad * 4 + r;
        int col = n0 + wn + ni * 16 + l16;
        Cz[(long)row * N + col] = acc[mi][ni][r];
      }
#undef SGA
#undef SGB
#undef RDA
#undef RDB
}

// ---------------- sum two split-K partials ----------------
__global__ void add2(const float* __restrict__ p0, const float* __restrict__ p1,
                     float* __restrict__ out, int n4) {
  int i = blockIdx.x * 256 + threadIdx.x;
  if (i < n4) {
    float4 a = ((const float4*)p0)[i];
    float4 b = ((const float4*)p1)[i];
    float4 o;
    o.x = a.x + b.x; o.y = a.y + b.y; o.z = a.z + b.z; o.w = a.w + b.w;
    ((float4*)out)[i] = o;
  }
}

// ---------------- beta / g projections + fused hidden bf16 cast --------------
__global__ __launch_bounds__(256) void small_proj(const float* __restrict__ hidden,
                                                  const float* __restrict__ Wba32,
                                                  const float* __restrict__ dt_bias,
                                                  const float* __restrict__ A_log,
                                                  float* __restrict__ betaT,
                                                  float* __restrict__ gT,
                                                  short* __restrict__ hbf) {
  __shared__ float red[2][32][33];
  int r0 = blockIdx.x * 2;
  int tid = threadIdx.x;
  int cg = tid & 7, s = tid >> 3;
  const f32x4* wp = (const f32x4*)Wba32 + (long)s * 64 * 8 + cg;
  const f32x4* h0 = (const f32x4*)(hidden + (long)r0 * D_ + s * 64);
  const f32x4* h1 = (const f32x4*)(hidden + (long)(r0 + 1) * D_ + s * 64);
  f32x4 a0 = {0.f, 0.f, 0.f, 0.f}, a1 = {0.f, 0.f, 0.f, 0.f};
#pragma unroll
  for (int ii = 0; ii < 16; ++ii) {
    f32x4 ha = h0[ii], hb = h1[ii];
    f32x4 w0 = wp[(ii * 4 + 0) * 8];
    f32x4 w1 = wp[(ii * 4 + 1) * 8];
    f32x4 w2 = wp[(ii * 4 + 2) * 8];
    f32x4 w3 = wp[(ii * 4 + 3) * 8];
    a0 += ha[0] * w0; a1 += hb[0] * w0;
    a0 += ha[1] * w1; a1 += hb[1] * w1;
    a0 += ha[2] * w2; a1 += hb[2] * w2;
    a0 += ha[3] * w3; a1 += hb[3] * w3;
  }
#pragma unroll
  for (int j = 0; j < 4; ++j) {
    red[0][s][cg * 4 + j] = a0[j];
    red[1][s][cg * 4 + j] = a1[j];
  }
  // fused bf16 cast of hidden rows r0, r0+1 (L1-hot re-reads, coalesced 16B/lane)
  {
    int colb = s * 64 + cg * 8;
    const float* p0 = hidden + (long)r0 * D_ + colb;
    const float* p1 = p0 + D_;
    float4 x0 = *(const float4*)(p0);
    float4 x1 = *(const float4*)(p0 + 4);
    float4 y0 = *(const float4*)(p1);
    float4 y1 = *(const float4*)(p1 + 4);
    short8 o0, o1;
    o0[0] = f2bf(x0.x); o0[1] = f2bf(x0.y); o0[2] = f2bf(x0.z); o0[3] = f2bf(x0.w);
    o0[4] = f2bf(x1.x); o0[5] = f2bf(x1.y); o0[6] = f2bf(x1.z); o0[7] = f2bf(x1.w);
    o1[0] = f2bf(y0.x); o1[1] = f2bf(y0.y); o1[2] = f2bf(y0.z); o1[3] = f2bf(y0.w);
    o1[4] = f2bf(y1.x); o1[5] = f2bf(y1.y); o1[6] = f2bf(y1.z); o1[7] = f2bf(y1.w);
    *(short8*)(hbf + (long)r0 * D_ + colb) = o0;
    *(short8*)(hbf + (long)(r0 + 1) * D_ + colb) = o1;
  }
  __syncthreads();
  if (tid < 64) {
    int row = tid >> 5, c = tid & 31;
    float t0 = 0.f, t1 = 0.f, t2 = 0.f, t3 = 0.f;
#pragma unroll
    for (int ss = 0; ss < 32; ss += 4) {
      t0 += red[row][ss][c];
      t1 += red[row][ss + 1][c];
      t2 += red[row][ss + 2][c];
      t3 += red[row][ss + 3][c];
    }
    float t = (t0 + t1) + (t2 + t3);
    int r = r0 + row;
    if (c < 16) {
      betaT[c * BT_ + r] = 1.f / (1.f + __expf(-t));
    } else {
      int hh = c - 16;
      float y = t + dt_bias[hh];
      float sp = fmaxf(y, 0.f) + log1pf(__expf(-fabsf(y)));
      gT[hh * BT_ + r] = -__expf(A_log[hh]) * sp;   // raw g (log decay)
    }
  }
}

// ---------------- depthwise causal conv (K=4) + SiLU ----------------
__global__ void conv_silu(const float* __restrict__ x, const float* __restrict__ w,
                          float* __restrict__ y) {
  int idx = blockIdx.x * 256 + threadIdx.x;
  int c = idx & (CONV_DIM_ - 1);
  int bt = idx >> 12;
  int t = bt & (T_ - 1);
  float4 wc = *(const float4*)(w + c * 4);
  const float* xp = x + (long)idx;
  float acc = wc.w * xp[0];
  if (t >= 1) acc += wc.z * xp[-CONV_DIM_];
  if (t >= 2) acc += wc.y * xp[-2 * CONV_DIM_];
  if (t >= 3) acc += wc.x * xp[-3 * CONV_DIM_];
  y[idx] = acc * (1.f / (1.f + __expf(-acc)));
}

// ---------------- q/k l2norm (+ q scale), bf16 out ----------------
__global__ __launch_bounds__(64) void qknorm(const float* __restrict__ qkv,
                                             short* __restrict__ qb, short* __restrict__ kb) {
  int bi = blockIdx.x;          // B*T*HK*2
  int which = bi & 1;
  int h = (bi >> 1) & 7;
  int bt = bi >> 4;
  int lane = threadIdx.x;
  const float* src = qkv + (long)bt * CONV_DIM_ + which * KEY_DIM_ + h * DK_;
  float2 v = *(const float2*)(src + lane * 2);
  float ss = v.x * v.x + v.y * v.y;
#pragma unroll
  for (int m = 32; m; m >>= 1) ss += __shfl_xor(ss, m, 64);
  float scale = rsqrtf(ss + 1e-6f);
  if (which == 0) scale *= 0.08838834764831845f;  // DK^-0.5
  short* dst = (which ? kb : qb) + ((long)bt * HK_ + h) * DK_;
  short2 o; o.x = f2bf(v.x * scale); o.y = f2bf(v.y * scale);
  ((short2*)dst)[lane] = o;
}

// ================= PHASE 1: per-chunk local quantities (parallel, 512 blocks)
__global__ __launch_bounds__(256, 2) void chunk_phase1(
    const short* __restrict__ qbf, const short* __restrict__ kbf,
    const float* __restrict__ qkv, const float* __restrict__ gT,
    const float* __restrict__ bT,
    short* __restrict__ Pm, short* __restrict__ GQ, short* __restrict__ KtT,
    short* __restrict__ Wneg, float* __restrict__ Ut, float* __restrict__ Gammac) {
  __shared__ float Al[64 * 64];      // 16 KB
  __shared__ float Gs[64], Gam[64], Dd[64], Bet[64], BG[64];

  int ci = blockIdx.x;
  int c = ci & 15, hv = (ci >> 4) & 15, b = ci >> 8;
  int hk = hv >> 1;
  int t0 = c * CL_;
  int tid = threadIdx.x;
  int wave = tid >> 6, lane = tid & 63, quad = lane >> 4, l16 = lane & 15;

  if (tid < 64) {
    float g = gT[(hv * B_ + b) * T_ + t0 + tid];
    float x = g;
#pragma unroll
    for (int off = 1; off < 64; off <<= 1) {
      float y = __shfl_up(x, off, 64);
      if (tid >= off) x += y;
    }
    Gs[tid] = x;
    float gm = __expf(x);
    Gam[tid] = gm;
    float Gtot = __shfl(x, 63, 64);
    Dd[tid] = __expf(Gtot - x);
    float bb = bT[(hv * B_ + b) * T_ + t0 + tid];
    Bet[tid] = bb;
    BG[tid] = bb * gm;
    if (tid == 63) Gammac[ci] = __expf(x);
  }
  __syncthreads();

  const long kbase = ((long)(b * T_ + t0) * HK_ + hk) * DK_;   // in shorts
  const int kstride = HK_ * DK_;                               // 1024

  int half = tid >> 7;        // 0 = V-columns, 1 = betaGammaK-columns
  int col = tid & 127;

  // ---- KK^T -> Al (mask s>r, scale beta_s * exp(G_s - G_r)) ----
  {
    f32x4 acc[4] = {};
#pragma unroll
    for (int kk = 0; kk < 4; ++kk) {
      short8 afr = *(const short8*)(kbf + kbase + (long)(16 * wave + l16) * kstride + kk * 32 + quad * 8);
#pragma unroll
      for (int j = 0; j < 4; ++j) {
        short8 bfr = *(const short8*)(kbf + kbase + (long)(16 * j + l16) * kstride + kk * 32 + quad * 8);
        acc[j] = __builtin_amdgcn_mfma_f32_16x16x32_bf16(afr, bfr, acc[j], 0, 0, 0);
      }
    }
#pragma unroll
    for (int j = 0; j < 4; ++j)
#pragma unroll
      for (int r = 0; r < 4; ++r) {
        int row = 16 * wave + quad * 4 + r, colx = 16 * j + l16;
        float v = 0.f;
        if (row > colx) v = Bet[row] * __expf(Gs[row] - Gs[colx]) * acc[j][r];
        Al[row * 64 + colx] = v;
      }
  }
  // ---- QK^T -> Pm (mask t>=s, scale exp(G_t - G_s)) ----
  {
    f32x4 acc[4] = {};
#pragma unroll
    for (int kk = 0; kk < 4; ++kk) {
      short8 afr = *(const short8*)(qbf + kbase + (long)(16 * wave + l16) * kstride + kk * 32 + quad * 8);
#pragma unroll
      for (int j = 0; j < 4; ++j) {
        short8 bfr = *(const short8*)(kbf + kbase + (long)(16 * j + l16) * kstride + kk * 32 + quad * 8);
        acc[j] = __builtin_amdgcn_mfma_f32_16x16x32_bf16(afr, bfr, acc[j], 0, 0, 0);
      }
    }
#pragma unroll
    for (int j = 0; j < 4; ++j)
#pragma unroll
      for (int r = 0; r < 4; ++r) {
        int row = 16 * wave + quad * 4 + r, colx = 16 * j + l16;
        float v = 0.f;
        if (row >= colx) v = __expf(Gs[row] - Gs[colx]) * acc[j][r];
        Pm[(long)ci * 4096 + row * 64 + colx] = f2bf(v);
      }
  }
  // ---- GQ[s][d] = Gam[s]*q[s][d] (coalesced short2 writes) ----
  for (int s = wave; s < 64; s += 4) {
    float gm = Gam[s];
    short2 qv = *(const short2*)(qbf + kbase + (long)s * kstride + lane * 2);
    short2 o;
    o.x = f2bf(bf2f(qv.x) * gm);
    o.y = f2bf(bf2f(qv.y) * gm);
    *(short2*)(GQ + (long)ci * 8192 + s * 128 + lane * 2) = o;
  }
  // ---- KtT[d][s] = k[s][d]*Dd[s] ----
  for (int d = wave; d < 128; d += 4) {
    float kv = bf2f(kbf[kbase + (long)lane * kstride + d]);
    KtT[(long)ci * 8192 + d * 64 + lane] = f2bf(kv * Dd[lane]);
  }

  // ---- RHS columns into registers (issued here: latency hides under the
  //      barrier; u[64] not live during the MFMA sections above) ----
  float u[64];
  {
    const float* vcol = qkv + (long)(b * T_ + t0) * CONV_DIM_ + 2 * KEY_DIM_ + hv * DV_ + col;
    const short* kcol = kbf + kbase + col;
    if (half == 0) {
#pragma unroll
      for (int r = 0; r < 64; ++r) u[r] = vcol[(long)r * CONV_DIM_];
    } else {
#pragma unroll
      for (int r = 0; r < 64; ++r) u[r] = bf2f(kcol[(long)r * kstride]);
    }
  }
  __syncthreads();   // Al complete

  // ---- scale RHS ----
  if (half == 0) {
#pragma unroll
    for (int r = 0; r < 64; ++r) u[r] *= Bet[r];
  } else {
#pragma unroll
    for (int r = 0; r < 64; ++r) u[r] *= BG[r];
  }

  // ---- right-looking blocked forward substitution ----
  // Per 4-col panel: tiny 4x4 triangular finalize, then streaming rank-4
  // updates (contiguous float4 broadcast reads, independent across s).
#pragma unroll
  for (int rb = 0; rb < 64; rb += 4) {
    {
      const float* A1 = Al + (rb + 1) * 64 + rb;
      const float* A2 = Al + (rb + 2) * 64 + rb;
      const float* A3 = Al + (rb + 3) * 64 + rb;
      u[rb + 1] -= A1[0] * u[rb];
      u[rb + 2] -= A2[0] * u[rb] + A2[1] * u[rb + 1];
      u[rb + 3] -= A3[0] * u[rb] + A3[1] * u[rb + 1] + A3[2] * u[rb + 2];
    }
    float u0 = u[rb], u1 = u[rb + 1], u2 = u[rb + 2], u3 = u[rb + 3];
#pragma unroll
    for (int s = rb + 4; s < 64; ++s) {
      float4 a4 = *(const float4*)(Al + s * 64 + rb);
      u[s] -= (a4.x * u0 + a4.y * u1) + (a4.z * u2 + a4.w * u3);
    }
  }

  // ---- write out (coalesced) ----
  if (half == 0) {
    float* up = Ut + (long)ci * 8192 + col;
#pragma unroll
    for (int s = 0; s < 64; ++s) up[s * 128] = u[s];
  } else {
    short* wp = Wneg + (long)ci * 8192 + col;
#pragma unroll
    for (int s = 0; s < 64; ++s) wp[s * 128] = f2bf(-u[s]);
  }
}

// ================= PHASE 2: state recurrence over chunks (256 blocks) ========
__global__ __launch_bounds__(256) void chunk_phase2(
    const short* __restrict__ Wneg, const float* __restrict__ Ut,
    const short* __restrict__ KtT, const float* __restrict__ Gammac,
    short* __restrict__ UTg, short* __restrict__ ScTg) {
  __shared__ short SLT[16 * 136];   // S^T slice [n 16][m 128 pad 136]
  __shared__ short ULT[16 * 72];    // U'^T slice [n 16][s 64 pad 72]
  int bi = blockIdx.x >> 3;          // b*16+hv
  int n0 = (blockIdx.x & 7) * 16;    // col-slice base
  int tid = threadIdx.x, wave = tid >> 6, lane = tid & 63, quad = lane >> 4, l16 = lane & 15;
  f32x4 S2[2] = {};   // rows 32*wave+16i+quad*4+r, col n0+l16

  long ci0 = (long)bi * NCH_;
  // preload chunk-0 operands
  short8 Wr[4]; f32x4 Ur; short8 Kr[2][2];
  {
    long ci = ci0;
#pragma unroll
    for (int kk = 0; kk < 4; ++kk)
      Wr[kk] = *(const short8*)(Wneg + ci * 8192 + (16 * wave + l16) * 128 + kk * 32 + quad * 8);
    const float* up = Ut + ci * 8192 + (16 * wave + quad * 4) * 128 + n0 + l16;
#pragma unroll
    for (int r = 0; r < 4; ++r) Ur[r] = up[r * 128];
#pragma unroll
    for (int kk = 0; kk < 2; ++kk)
#pragma unroll
      for (int i = 0; i < 2; ++i)
        Kr[kk][i] = *(const short8*)(KtT + ci * 8192 + (32 * wave + 16 * i + l16) * 64 + kk * 32 + quad * 8);
  }

  for (int ch = 0; ch < NCH_; ++ch) {
    long ci = ci0 + ch;
    // 1. write S^T slice to LDS + global
#pragma unroll
    for (int i = 0; i < 2; ++i) {
      int m0 = 32 * wave + 16 * i + quad * 4;
      short4 p;
      p.x = f2bf(S2[i][0]); p.y = f2bf(S2[i][1]);
      p.z = f2bf(S2[i][2]); p.w = f2bf(S2[i][3]);
      *(short4*)(SLT + l16 * 136 + m0) = p;
      *(short4*)(ScTg + ci * 16384 + (n0 + l16) * 128 + m0) = p;
    }
    // prefetch next-chunk operands into registers (overlaps barriers + MFMA)
    short8 Wn[4]; f32x4 Un; short8 Kn[2][2];
    if (ch + 1 < NCH_) {
      long cj = ci + 1;
#pragma unroll
      for (int kk = 0; kk < 4; ++kk)
        Wn[kk] = *(const short8*)(Wneg + cj * 8192 + (16 * wave + l16) * 128 + kk * 32 + quad * 8);
      const float* up = Ut + cj * 8192 + (16 * wave + quad * 4) * 128 + n0 + l16;
#pragma unroll
      for (int r = 0; r < 4; ++r) Un[r] = up[r * 128];
#pragma unroll
      for (int kk = 0; kk < 2; ++kk)
#pragma unroll
        for (int i = 0; i < 2; ++i)
          Kn[kk][i] = *(const short8*)(KtT + cj * 8192 + (32 * wave + 16 * i + l16) * 64 + kk * 32 + quad * 8);
    }
    __syncthreads();
    // 2. U' = U - W @ S^T  (contraction over m=128)
    f32x4 Ua = Ur;
#pragma unroll
    for (int kk = 0; kk < 4; ++kk) {
      short8 bfv = *(const short8*)(SLT + l16 * 136 + kk * 32 + quad * 8);
      Ua = __builtin_amdgcn_mfma_f32_16x16x32_bf16(Wr[kk], bfv, Ua, 0, 0, 0);
    }
    {
      int s0 = 16 * wave + quad * 4;
      short4 p;
      p.x = f2bf(Ua[0]); p.y = f2bf(Ua[1]); p.z = f2bf(Ua[2]); p.w = f2bf(Ua[3]);
      *(short4*)(ULT + l16 * 72 + s0) = p;
      *(short4*)(UTg + ci * 8192 + (n0 + l16) * 64 + s0) = p;
    }
    __syncthreads();
    // 3. S = S*gamma + KtT @ U'^T  (contraction over s=64)
    float gc = Gammac[ci];
#pragma unroll
    for (int i = 0; i < 2; ++i)
#pragma unroll
      for (int r = 0; r < 4; ++r) S2[i][r] *= gc;
#pragma unroll
    for (int kk = 0; kk < 2; ++kk) {
      short8 bfv = *(const short8*)(ULT + l16 * 72 + kk * 32 + quad * 8);
#pragma unroll
      for (int i = 0; i < 2; ++i)
        S2[i] = __builtin_amdgcn_mfma_f32_16x16x32_bf16(Kr[kk][i], bfv, S2[i], 0, 0, 0);
    }
    __syncthreads();
    if (ch + 1 < NCH_) {
#pragma unroll
      for (int kk = 0; kk < 4; ++kk) Wr[kk] = Wn[kk];
      Ur = Un;
#pragma unroll
      for (int kk = 0; kk < 2; ++kk)
#pragma unroll
        for (int i = 0; i < 2; ++i) Kr[kk][i] = Kn[kk][i];
    }
  }
}

// ================= PHASE 3: outputs + fused gated RMSNorm (512 blocks) =======
__global__ __launch_bounds__(256) void chunk_phase3(
    const short* __restrict__ GQ, const short* __restrict__ ScTg,
    const short* __restrict__ Pm, const short* __restrict__ UTg,
    const float* __restrict__ zbuf, const float* __restrict__ nw,
    short* __restrict__ obf) {
  int ci = blockIdx.x;
  int c = ci & 15, hv = (ci >> 4) & 15, b = ci >> 8;
  int t0 = c * CL_;
  int tid = threadIdx.x, wave = tid >> 6, lane = tid & 63, quad = lane >> 4, l16 = lane & 15;
  f32x4 acc[8] = {};
#pragma unroll
  for (int kk = 0; kk < 4; ++kk) {
    short8 af = *(const short8*)(GQ + (long)ci * 8192 + (16 * wave + l16) * 128 + kk * 32 + quad * 8);
#pragma unroll
    for (int j = 0; j < 8; ++j) {
      short8 bfv = *(const short8*)(ScTg + (long)ci * 16384 + (16 * j + l16) * 128 + kk * 32 + quad * 8);
      acc[j] = __builtin_amdgcn_mfma_f32_16x16x32_bf16(af, bfv, acc[j], 0, 0, 0);
    }
  }
#pragma unroll
  for (int kk = 0; kk < 2; ++kk) {
    short8 af = *(const short8*)(Pm + (long)ci * 4096 + (16 * wave + l16) * 64 + kk * 32 + quad * 8);
#pragma unroll
    for (int j = 0; j < 8; ++j) {
      short8 bfv = *(const short8*)(UTg + (long)ci * 8192 + (16 * j + l16) * 64 + kk * 32 + quad * 8);
      acc[j] = __builtin_amdgcn_mfma_f32_16x16x32_bf16(af, bfv, acc[j], 0, 0, 0);
    }
  }
  // fused gated RMSNorm * silu(z) epilogue.
#pragma unroll
  for (int r = 0; r < 4; ++r) {
    float ss = 0.f;
#pragma unroll
    for (int j = 0; j < 8; ++j) ss += acc[j][r] * acc[j][r];
    ss += __shfl_xor(ss, 1, 64);
    ss += __shfl_xor(ss, 2, 64);
    ss += __shfl_xor(ss, 4, 64);
    ss += __shfl_xor(ss, 8, 64);
    float scale = rsqrtf(ss * (1.f / 128.f) + 1e-6f);
    int t = t0 + 16 * wave + quad * 4 + r;
    long base = (long)(b * T_ + t) * VALUE_DIM_ + hv * DV_;
#pragma unroll
    for (int j = 0; j < 8; ++j) {
      int n = 16 * j + l16;
      float zv = zbuf[base + n];
      float sz = zv * (1.f / (1.f + __expf(-zv)));
      obf[base + n] = f2bf(acc[j][r] * scale * nw[n] * sz);
    }
  }
}

// ---------------- launcher ----------------
extern "C" void kernel_launch(void* const* d_in, const int* in_sizes, int n_in,
                              void* d_out, int out_size, void* d_ws, size_t ws_size,
                              hipStream_t stream) {
  const float* hidden  = (const float*)d_in[0];
  const float* W_qkv   = (const float*)d_in[1];
  const float* W_z     = (const float*)d_in[2];
  const float* W_b     = (const float*)d_in[3];
  const float* W_a     = (const float*)d_in[4];
  const float* conv_w  = (const float*)d_in[5];
  const float* dt_bias = (const float*)d_in[6];
  const float* A_log   = (const float*)d_in[7];
  const float* norm_w  = (const float*)d_in[8];
  const float* W_out   = (const float*)d_in[9];
  float* out = (float*)d_out;

  char* ws = (char*)d_ws;
  size_t off = 0;
  auto alloc = [&](size_t bytes) {
    void* p = ws + off;
    off += (bytes + 255) & ~(size_t)255;
    return p;
  };
  short* hidden_bf = (short*)alloc((size_t)BT_ * D_ * 2);           // 8 MB
  short* WcatT     = (short*)alloc((size_t)(CONV_DIM_ + VALUE_DIM_) * D_ * 2); // 24 MB
  short* WoutT     = (short*)alloc((size_t)D_ * VALUE_DIM_ * 2);    // 8 MB
  float* mixed     = (float*)alloc((size_t)BT_ * CONV_DIM_ * 4);    // 32 MB
  float* qkv       = (float*)alloc((size_t)BT_ * CONV_DIM_ * 4);    // 32 MB
  float* zbuf      = (float*)alloc((size_t)BT_ * VALUE_DIM_ * 4);   // 16 MB
  short* qbf       = (short*)alloc((size_t)BT_ * KEY_DIM_ * 2);     // 4 MB
  short* kbf       = (short*)alloc((size_t)BT_ * KEY_DIM_ * 2);     // 4 MB
  float* betab     = (float*)alloc((size_t)BT_ * HV_ * 4);
  float* gb        = (float*)alloc((size_t)BT_ * HV_ * 4);
  float* Wba32     = (float*)alloc((size_t)D_ * 32 * 4);            // 256 KB
  short* Wneg      = (short*)alloc((size_t)512 * 8192 * 2);         // 8 MB
  float* Ut32      = (float*)alloc((size_t)512 * 8192 * 4);         // 16 MB
  short* KtT       = (short*)alloc((size_t)512 * 8192 * 2);         // 8 MB
  short* UTg       = (short*)alloc((size_t)512 * 8192 * 2);         // 8 MB
  short* ScTg      = (short*)alloc((size_t)512 * 16384 * 2);        // 16 MB
  float* Gammac    = (float*)alloc((size_t)512 * 4);
  // aliases (into buffers dead by the time they're written):
  short* Pm   = (short*)(mixed + (size_t)BT_ * VALUE_DIM_);         // 4 MB (mixed dead after conv)
  short* GQ   = Pm + (size_t)512 * 4096;                            // 8 MB
  short* obf  = hidden_bf;          // dead after fused qkv+z GEMM
  float* Cpart = qkv;               // 32 MB; qkv dead after phase1 (split-K partials)

  dim3 tb32(32, 8);
  transpose_cast<<<dim3(CONV_DIM_ / 32, D_ / 32), tb32, 0, stream>>>(W_qkv, WcatT, D_, CONV_DIM_);
  transpose_cast<<<dim3(VALUE_DIM_ / 32, D_ / 32), tb32, 0, stream>>>(W_z, WcatT + (size_t)CONV_DIM_ * D_, D_, VALUE_DIM_);
  transpose_cast<<<dim3(D_ / 32, VALUE_DIM_ / 32), tb32, 0, stream>>>(W_out, WoutT, VALUE_DIM_, D_);
  interleave_ba<<<32 * D_ / 256, 256, 0, stream>>>(W_b, W_a, Wba32);

  // beta/g projections + fused hidden bf16 cast (must precede the GEMM)
  small_proj<<<BT_ / 2, 256, 0, stream>>>(hidden, Wba32, dt_bias, A_log, betab, gb, hidden_bf);

  // fused qkv + z projection: 256x192 8-phase, grid 32x8 = 256 blocks (1/CU)
  gemm256n192<<<dim3((CONV_DIM_ + VALUE_DIM_) / 192, BT_ / 256), 512, 0, stream>>>(
      hidden_bf, WcatT, mixed, zbuf, CONV_DIM_, VALUE_DIM_, D_);
  conv_silu<<<BT_ * CONV_DIM_ / 256, 256, 0, stream>>>(mixed, conv_w, qkv);
  qknorm<<<BT_ * HK_ * 2, 64, 0, stream>>>(qkv, qbf, kbf);

  chunk_phase1<<<512, 256, 0, stream>>>(qbf, kbf, qkv, gb, betab, Pm, GQ, KtT, Wneg, Ut32, Gammac);
  chunk_phase2<<<256, 256, 0, stream>>>(Wneg, Ut32, KtT, Gammac, UTg, ScTg);
  chunk_phase3<<<512, 256, 0, stream>>>(GQ, ScTg, Pm, UTg, zbuf, norm_w, obf);

  // out projection: 256x128 8-phase split-K=2 -> 256 blocks, then partial-sum
  gemm256ks<<<dim3(D_ / 128, BT_ / 256, 2), 512, 0, stream>>>(obf, WoutT, Cpart, BT_, D_, VALUE_DIM_);
  add2<<<(BT_ * D_ / 4 + 255) / 256, 256, 0, stream>>>(Cpart, Cpart + (size_t)BT_ * D_, out, BT_ * D_ / 4);
}

// Round 6
// 355.504 us; speedup vs baseline: 1.0666x; 1.0263x over previous
//
#include <hip/hip_runtime.h>
#include <hip/hip_bf16.h>

// GatedDeltaNet: B=2, T=1024, D=2048, HK=8, HV=16, DK=DV=128, KW=4
#define B_ 2
#define T_ 1024
#define D_ 2048
#define HK_ 8
#define HV_ 16
#define DK_ 128
#define DV_ 128
#define KEY_DIM_ 1024
#define VALUE_DIM_ 2048
#define CONV_DIM_ 4096
#define BT_ 2048   // B*T
#define NCH_ 16    // chunks per sequence (T/64)
#define CL_ 64     // chunk length

typedef __attribute__((ext_vector_type(8))) short short8;
typedef __attribute__((ext_vector_type(4))) float f32x4;

__device__ __forceinline__ short f2bf(float x) {
  __hip_bfloat16 h = __float2bfloat16(x);
  return *reinterpret_cast<short*>(&h);
}
__device__ __forceinline__ float bf2f(short u) {
  unsigned int x = ((unsigned int)(unsigned short)u) << 16;
  return __int_as_float(x);
}

#define GLOAD_LDS16(g, l)                                             \
  __builtin_amdgcn_global_load_lds(                                   \
      (const __attribute__((address_space(1))) void*)(g),             \
      (__attribute__((address_space(3))) void*)(l), 16, 0, 0)

// ---------------- merged weight prep: 3 transposes + interleave --------------
// z=0: W_qkv -> WcatT[0:CONV*D], z=1: W_z -> WcatT[CONV*D:], z=2: W_out -> WoutT
// z=3: interleave W_b|W_a -> Wba32
__global__ void prep_weights(const float* __restrict__ Wqkv, const float* __restrict__ Wz,
                             const float* __restrict__ Wout, const float* __restrict__ Wb,
                             const float* __restrict__ Wa,
                             short* __restrict__ WcatT, short* __restrict__ WoutT,
                             float* __restrict__ Wba32) {
  __shared__ float tile[32][33];
  int z = blockIdx.z;
  int tx = threadIdx.x, ty = threadIdx.y;
  if (z == 3) {
    if (blockIdx.y != 0 || blockIdx.x >= 64) return;
    int tid = ty * 32 + tx;
    int base = blockIdx.x * 1024 + tid * 4;
    float4 o;
#pragma unroll
    for (int j = 0; j < 4; ++j) {
      int i = base + j;
      int c = i & 31, k = i >> 5;
      ((float*)&o)[j] = (c < 16) ? Wb[k * 16 + c] : Wa[k * 16 + (c - 16)];
    }
    *(float4*)(Wba32 + base) = o;
    return;
  }
  const float* W; short* WT; int R, C;
  if (z == 0)      { W = Wqkv; WT = WcatT;                            R = D_;         C = CONV_DIM_; }
  else if (z == 1) { W = Wz;   WT = WcatT + (size_t)CONV_DIM_ * D_;   R = D_;         C = VALUE_DIM_; }
  else             { W = Wout; WT = WoutT;                            R = VALUE_DIM_; C = D_; }
  if (blockIdx.x * 32 >= C) return;
  int x = blockIdx.x * 32 + tx;
#pragma unroll
  for (int j = 0; j < 4; ++j) {
    int r = blockIdx.y * 32 + ty + j * 8;
    tile[ty + j * 8][tx] = W[(long)r * C + x];
  }
  __syncthreads();
  int ro = blockIdx.y * 32 + tx;
#pragma unroll
  for (int j = 0; j < 4; ++j) {
    int co = blockIdx.x * 32 + ty + j * 8;
    WT[(long)co * R + ro] = f2bf(tile[tx][ty + j * 8]);
  }
}

#define MFMA_(d, x, y) d = __builtin_amdgcn_mfma_f32_16x16x32_bf16(x, y, d, 0, 0, 0)
#define BAR_() do { __builtin_amdgcn_s_barrier(); __builtin_amdgcn_sched_barrier(0); } while (0)
#define PRIO_ON_() __builtin_amdgcn_s_setprio(1)
#define PRIO_OFF_() do { __builtin_amdgcn_s_setprio(0); __builtin_amdgcn_sched_barrier(0); } while (0)

// ========== 256x192 8-phase GEMM (grid 32x8 = 256 blocks = 1/CU) ============
__global__ __launch_bounds__(512) void gemm256n192(const short* __restrict__ A,
                                                   const short* __restrict__ Bt,
                                                   float* __restrict__ C0,
                                                   float* __restrict__ C1,
                                                   int N0, int N1, int K) {
  __shared__ short lds[57344];   // 2 bufs x 28672 shorts (A 16384 | B 12288)
  const int tid = threadIdx.x;
  const int lane = tid & 63, wid = tid >> 6;
  const int quad = lane >> 4, l16 = lane & 15;
  const int wm = (wid >> 1) * 64, wn = (wid & 1) * 96;
  const int m0 = blockIdx.y * 256, n0 = blockIdx.x * 192;

  const int r8 = tid >> 3, t8 = (tid & 7) * 8;
  const int csw = t8 ^ ((r8 & 7) << 3);
  const int cswr = (quad ^ (l16 & 7)) << 3;
  const int NIT = K >> 7;   // 2 K-tiles per iteration

  f32x4 acc[4][6] = {};
  short8 a[4][2], bl[3][2], bh[3][2];

#define SGA(p, kt, rb) GLOAD_LDS16(A + (long)(m0 + (rb) + r8) * K + (kt) * 64 + csw, \
                                   lds + (p) * 28672 + ((rb) + r8) * 64 + t8)
#define SGB(p, kt, rb) GLOAD_LDS16(Bt + (long)(n0 + (rb) + r8) * K + (kt) * 64 + csw, \
                                   lds + (p) * 28672 + 16384 + ((rb) + r8) * 64 + t8)
#define RDA(p, r, kk) (*(const short8*)(lds + (p) * 28672 + (r) * 64 + (cswr ^ ((kk) << 5))))
#define RDB(p, r, kk) (*(const short8*)(lds + (p) * 28672 + 16384 + (r) * 64 + (cswr ^ ((kk) << 5))))

  // prologue: tile0 full (7), tile1 minus last B unit (6) -> 13 outstanding
  SGA(0, 0, 0); SGA(0, 0, 64); SGA(0, 0, 128); SGA(0, 0, 192);
  SGB(0, 0, 0); SGB(0, 0, 64); SGB(0, 0, 128);
  SGA(1, 1, 0); SGA(1, 1, 64); SGA(1, 1, 128); SGA(1, 1, 192);
  SGB(1, 1, 0); SGB(1, 1, 64);
  asm volatile("s_waitcnt vmcnt(6)" ::: "memory");
  BAR_();

#pragma unroll 1
  for (int i = 0; i < NIT; ++i) {
    const int tb = 2 * i + 1, tc = 2 * i + 2, td = 2 * i + 3;
    const bool more = (i + 1 < NIT);

    // ---- ph1: buf0, m01 x n-lo ----
#pragma unroll
    for (int mi = 0; mi < 2; ++mi) {
      a[mi][0] = RDA(0, wm + mi * 16 + l16, 0);
      a[mi][1] = RDA(0, wm + mi * 16 + l16, 1);
    }
#pragma unroll
    for (int ni = 0; ni < 3; ++ni) {
      bl[ni][0] = RDB(0, wn + ni * 16 + l16, 0);
      bl[ni][1] = RDB(0, wn + ni * 16 + l16, 1);
    }
    SGB(1, tb, 128);           // deferred last B unit of tile tb (buf1)
    BAR_();
    PRIO_ON_();
#pragma unroll
    for (int mi = 0; mi < 2; ++mi)
#pragma unroll
      for (int ni = 0; ni < 3; ++ni) {
        MFMA_(acc[mi][ni], a[mi][0], bl[ni][0]);
        MFMA_(acc[mi][ni], a[mi][1], bl[ni][1]);
      }
    PRIO_OFF_();
    __builtin_amdgcn_s_barrier();

    // ---- ph2: buf0, m23 x n-lo ----
    __builtin_amdgcn_sched_barrier(0);
#pragma unroll
    for (int mi = 2; mi < 4; ++mi) {
      a[mi][0] = RDA(0, wm + mi * 16 + l16, 0);
      a[mi][1] = RDA(0, wm + mi * 16 + l16, 1);
    }
    BAR_();
    PRIO_ON_();
#pragma unroll
    for (int mi = 2; mi < 4; ++mi)
#pragma unroll
      for (int ni = 0; ni < 3; ++ni) {
        MFMA_(acc[mi][ni], a[mi][0], bl[ni][0]);
        MFMA_(acc[mi][ni], a[mi][1], bl[ni][1]);
      }
    PRIO_OFF_();
    __builtin_amdgcn_s_barrier();

    // ---- ph3: buf0, m01 x n-hi ----
    __builtin_amdgcn_sched_barrier(0);
#pragma unroll
    for (int ni = 0; ni < 3; ++ni) {
      bh[ni][0] = RDB(0, wn + 48 + ni * 16 + l16, 0);
      bh[ni][1] = RDB(0, wn + 48 + ni * 16 + l16, 1);
    }
    if (more) { SGA(0, tc, 0); SGA(0, tc, 64); }
    BAR_();
    PRIO_ON_();
#pragma unroll
    for (int mi = 0; mi < 2; ++mi)
#pragma unroll
      for (int ni = 0; ni < 3; ++ni) {
        MFMA_(acc[mi][3 + ni], a[mi][0], bh[ni][0]);
        MFMA_(acc[mi][3 + ni], a[mi][1], bh[ni][1]);
      }
    PRIO_OFF_();
    __builtin_amdgcn_s_barrier();

    // ---- ph4: buf0, m23 x n-hi ----
    __builtin_amdgcn_sched_barrier(0);
    if (more) { SGA(0, tc, 128); SGA(0, tc, 192); SGB(0, tc, 0); SGB(0, tc, 64); }
    BAR_();
    PRIO_ON_();
#pragma unroll
    for (int mi = 2; mi < 4; ++mi)
#pragma unroll
      for (int ni = 0; ni < 3; ++ni) {
        MFMA_(acc[mi][3 + ni], a[mi][0], bh[ni][0]);
        MFMA_(acc[mi][3 + ni], a[mi][1], bh[ni][1]);
      }
    PRIO_OFF_();
    if (more) { asm volatile("s_waitcnt vmcnt(6)" ::: "memory"); }
    else      { asm volatile("s_waitcnt vmcnt(0)" ::: "memory"); }
    __builtin_amdgcn_s_barrier();

    // ---- ph5: buf1, m01 x n-lo ----
    __builtin_amdgcn_sched_barrier(0);
#pragma unroll
    for (int mi = 0; mi < 2; ++mi) {
      a[mi][0] = RDA(1, wm + mi * 16 + l16, 0);
      a[mi][1] = RDA(1, wm + mi * 16 + l16, 1);
    }
#pragma unroll
    for (int ni = 0; ni < 3; ++ni) {
      bl[ni][0] = RDB(1, wn + ni * 16 + l16, 0);
      bl[ni][1] = RDB(1, wn + ni * 16 + l16, 1);
    }
    if (more) SGB(0, tc, 128);
    BAR_();
    PRIO_ON_();
#pragma unroll
    for (int mi = 0; mi < 2; ++mi)
#pragma unroll
      for (int ni = 0; ni < 3; ++ni) {
        MFMA_(acc[mi][ni], a[mi][0], bl[ni][0]);
        MFMA_(acc[mi][ni], a[mi][1], bl[ni][1]);
      }
    PRIO_OFF_();
    __builtin_amdgcn_s_barrier();

    // ---- ph6: buf1, m23 x n-lo ----
    __builtin_amdgcn_sched_barrier(0);
#pragma unroll
    for (int mi = 2; mi < 4; ++mi) {
      a[mi][0] = RDA(1, wm + mi * 16 + l16, 0);
      a[mi][1] = RDA(1, wm + mi * 16 + l16, 1);
    }
    BAR_();
    PRIO_ON_();
#pragma unroll
    for (int mi = 2; mi < 4; ++mi)
#pragma unroll
      for (int ni = 0; ni < 3; ++ni) {
        MFMA_(acc[mi][ni], a[mi][0], bl[ni][0]);
        MFMA_(acc[mi][ni], a[mi][1], bl[ni][1]);
      }
    PRIO_OFF_();
    __builtin_amdgcn_s_barrier();

    // ---- ph7: buf1, m01 x n-hi ----
    __builtin_amdgcn_sched_barrier(0);
#pragma unroll
    for (int ni = 0; ni < 3; ++ni) {
      bh[ni][0] = RDB(1, wn + 48 + ni * 16 + l16, 0);
      bh[ni][1] = RDB(1, wn + 48 + ni * 16 + l16, 1);
    }
    if (more) { SGA(1, td, 0); SGA(1, td, 64); }
    BAR_();
    PRIO_ON_();
#pragma unroll
    for (int mi = 0; mi < 2; ++mi)
#pragma unroll
      for (int ni = 0; ni < 3; ++ni) {
        MFMA_(acc[mi][3 + ni], a[mi][0], bh[ni][0]);
        MFMA_(acc[mi][3 + ni], a[mi][1], bh[ni][1]);
      }
    PRIO_OFF_();
    __builtin_amdgcn_s_barrier();

    // ---- ph8: buf1, m23 x n-hi ----
    __builtin_amdgcn_sched_barrier(0);
    if (more) { SGA(1, td, 128); SGA(1, td, 192); SGB(1, td, 0); SGB(1, td, 64); }
    BAR_();
    PRIO_ON_();
#pragma unroll
    for (int mi = 2; mi < 4; ++mi)
#pragma unroll
      for (int ni = 0; ni < 3; ++ni) {
        MFMA_(acc[mi][3 + ni], a[mi][0], bh[ni][0]);
        MFMA_(acc[mi][3 + ni], a[mi][1], bh[ni][1]);
      }
    PRIO_OFF_();
    if (more) { asm volatile("s_waitcnt vmcnt(6)" ::: "memory"); }
    else      { asm volatile("s_waitcnt vmcnt(0)" ::: "memory"); }
    __builtin_amdgcn_s_barrier();
    __builtin_amdgcn_sched_barrier(0);
  }

#pragma unroll
  for (int mi = 0; mi < 4; ++mi)
#pragma unroll
    for (int ni = 0; ni < 6; ++ni)
#pragma unroll
      for (int r = 0; r < 4; ++r) {
        int row = m0 + wm + mi * 16 + quad * 4 + r;
        int col = n0 + wn + ni * 16 + l16;
        if (col < N0) C0[(long)row * N0 + col] = acc[mi][ni][r];
        else          C1[(long)row * N1 + (col - N0)] = acc[mi][ni][r];
      }
#undef SGA
#undef SGB
#undef RDA
#undef RDB
}

// ========== 256x128 8-phase GEMM, split-K=2 (grid 16x8x2 = 256 blocks) ======
__global__ __launch_bounds__(512) void gemm256ks(const short* __restrict__ Ag,
                                                 const short* __restrict__ Btg,
                                                 float* __restrict__ Cp,
                                                 int M, int N, int K) {
  __shared__ short lds[49152];   // 2 bufs x 24576 shorts (A 16384 | B 8192)
  const int tid = threadIdx.x;
  const int lane = tid & 63, wid = tid >> 6;
  const int quad = lane >> 4, l16 = lane & 15;
  const int wm = (wid >> 1) * 64, wn = (wid & 1) * 64;
  const int m0 = blockIdx.y * 256, n0 = blockIdx.x * 128;
  const int kh = K >> 1;
  const short* A = Ag + blockIdx.z * kh;    // column offset into K
  const short* Bt = Btg + blockIdx.z * kh;

  const int r8 = tid >> 3, t8 = (tid & 7) * 8;
  const int csw = t8 ^ ((r8 & 7) << 3);
  const int cswr = (quad ^ (l16 & 7)) << 3;
  const int NIT = kh >> 7;

  f32x4 acc[4][4] = {};
  short8 a[4][2], bl[2][2], bh[2][2];

#define SGA(p, kt, rb) GLOAD_LDS16(A + (long)(m0 + (rb) + r8) * K + (kt) * 64 + csw, \
                                   lds + (p) * 24576 + ((rb) + r8) * 64 + t8)
#define SGB(p, kt, rb) GLOAD_LDS16(Bt + (long)(n0 + (rb) + r8) * K + (kt) * 64 + csw, \
                                   lds + (p) * 24576 + 16384 + ((rb) + r8) * 64 + t8)
#define RDA(p, r, kk) (*(const short8*)(lds + (p) * 24576 + (r) * 64 + (cswr ^ ((kk) << 5))))
#define RDB(p, r, kk) (*(const short8*)(lds + (p) * 24576 + 16384 + (r) * 64 + (cswr ^ ((kk) << 5))))

  // prologue: tile0 full (6), tile1 minus last B unit (5) -> 11 outstanding
  SGA(0, 0, 0); SGA(0, 0, 64); SGA(0, 0, 128); SGA(0, 0, 192);
  SGB(0, 0, 0); SGB(0, 0, 64);
  SGA(1, 1, 0); SGA(1, 1, 64); SGA(1, 1, 128); SGA(1, 1, 192);
  SGB(1, 1, 0);
  asm volatile("s_waitcnt vmcnt(5)" ::: "memory");
  BAR_();

#pragma unroll 1
  for (int i = 0; i < NIT; ++i) {
    const int tb = 2 * i + 1, tc = 2 * i + 2, td = 2 * i + 3;
    const bool more = (i + 1 < NIT);

    // ---- ph1 ----
#pragma unroll
    for (int mi = 0; mi < 2; ++mi) {
      a[mi][0] = RDA(0, wm + mi * 16 + l16, 0);
      a[mi][1] = RDA(0, wm + mi * 16 + l16, 1);
    }
#pragma unroll
    for (int ni = 0; ni < 2; ++ni) {
      bl[ni][0] = RDB(0, wn + ni * 16 + l16, 0);
      bl[ni][1] = RDB(0, wn + ni * 16 + l16, 1);
    }
    SGB(1, tb, 64);
    BAR_();
    PRIO_ON_();
#pragma unroll
    for (int mi = 0; mi < 2; ++mi)
#pragma unroll
      for (int ni = 0; ni < 2; ++ni) {
        MFMA_(acc[mi][ni], a[mi][0], bl[ni][0]);
        MFMA_(acc[mi][ni], a[mi][1], bl[ni][1]);
      }
    PRIO_OFF_();
    __builtin_amdgcn_s_barrier();

    // ---- ph2 ----
    __builtin_amdgcn_sched_barrier(0);
#pragma unroll
    for (int mi = 2; mi < 4; ++mi) {
      a[mi][0] = RDA(0, wm + mi * 16 + l16, 0);
      a[mi][1] = RDA(0, wm + mi * 16 + l16, 1);
    }
    BAR_();
    PRIO_ON_();
#pragma unroll
    for (int mi = 2; mi < 4; ++mi)
#pragma unroll
      for (int ni = 0; ni < 2; ++ni) {
        MFMA_(acc[mi][ni], a[mi][0], bl[ni][0]);
        MFMA_(acc[mi][ni], a[mi][1], bl[ni][1]);
      }
    PRIO_OFF_();
    __builtin_amdgcn_s_barrier();

    // ---- ph3 ----
    __builtin_amdgcn_sched_barrier(0);
#pragma unroll
    for (int ni = 0; ni < 2; ++ni) {
      bh[ni][0] = RDB(0, wn + 32 + ni * 16 + l16, 0);
      bh[ni][1] = RDB(0, wn + 32 + ni * 16 + l16, 1);
    }
    if (more) { SGA(0, tc, 0); SGA(0, tc, 64); }
    BAR_();
    PRIO_ON_();
#pragma unroll
    for (int mi = 0; mi < 2; ++mi)
#pragma unroll
      for (int ni = 0; ni < 2; ++ni) {
        MFMA_(acc[mi][2 + ni], a[mi][0], bh[ni][0]);
        MFMA_(acc[mi][2 + ni], a[mi][1], bh[ni][1]);
      }
    PRIO_OFF_();
    __builtin_amdgcn_s_barrier();

    // ---- ph4 ----
    __builtin_amdgcn_sched_barrier(0);
    if (more) { SGA(0, tc, 128); SGA(0, tc, 192); SGB(0, tc, 0); }
    BAR_();
    PRIO_ON_();
#pragma unroll
    for (int mi = 2; mi < 4; ++mi)
#pragma unroll
      for (int ni = 0; ni < 2; ++ni) {
        MFMA_(acc[mi][2 + ni], a[mi][0], bh[ni][0]);
        MFMA_(acc[mi][2 + ni], a[mi][1], bh[ni][1]);
      }
    PRIO_OFF_();
    if (more) { asm volatile("s_waitcnt vmcnt(5)" ::: "memory"); }
    else      { asm volatile("s_waitcnt vmcnt(0)" ::: "memory"); }
    __builtin_amdgcn_s_barrier();

    // ---- ph5 ----
    __builtin_amdgcn_sched_barrier(0);
#pragma unroll
    for (int mi = 0; mi < 2; ++mi) {
      a[mi][0] = RDA(1, wm + mi * 16 + l16, 0);
      a[mi][1] = RDA(1, wm + mi * 16 + l16, 1);
    }
#pragma unroll
    for (int ni = 0; ni < 2; ++ni) {
      bl[ni][0] = RDB(1, wn + ni * 16 + l16, 0);
      bl[ni][1] = RDB(1, wn + ni * 16 + l16, 1);
    }
    if (more) SGB(0, tc, 64);
    BAR_();
    PRIO_ON_();
#pragma unroll
    for (int mi = 0; mi < 2; ++mi)
#pragma unroll
      for (int ni = 0; ni < 2; ++ni) {
        MFMA_(acc[mi][ni], a[mi][0], bl[ni][0]);
        MFMA_(acc[mi][ni], a[mi][1], bl[ni][1]);
      }
    PRIO_OFF_();
    __builtin_amdgcn_s_barrier();

    // ---- ph6 ----
    __builtin_amdgcn_sched_barrier(0);
#pragma unroll
    for (int mi = 2; mi < 4; ++mi) {
      a[mi][0] = RDA(1, wm + mi * 16 + l16, 0);
      a[mi][1] = RDA(1, wm + mi * 16 + l16, 1);
    }
    BAR_();
    PRIO_ON_();
#pragma unroll
    for (int mi = 2; mi < 4; ++mi)
#pragma unroll
      for (int ni = 0; ni < 2; ++ni) {
        MFMA_(acc[mi][ni], a[mi][0], bl[ni][0]);
        MFMA_(acc[mi][ni], a[mi][1], bl[ni][1]);
      }
    PRIO_OFF_();
    __builtin_amdgcn_s_barrier();

    // ---- ph7 ----
    __builtin_amdgcn_sched_barrier(0);
#pragma unroll
    for (int ni = 0; ni < 2; ++ni) {
      bh[ni][0] = RDB(1, wn + 32 + ni * 16 + l16, 0);
      bh[ni][1] = RDB(1, wn + 32 + ni * 16 + l16, 1);
    }
    if (more) { SGA(1, td, 0); SGA(1, td, 64); }
    BAR_();
    PRIO_ON_();
#pragma unroll
    for (int mi = 0; mi < 2; ++mi)
#pragma unroll
      for (int ni = 0; ni < 2; ++ni) {
        MFMA_(acc[mi][2 + ni], a[mi][0], bh[ni][0]);
        MFMA_(acc[mi][2 + ni], a[mi][1], bh[ni][1]);
      }
    PRIO_OFF_();
    __builtin_amdgcn_s_barrier();

    // ---- ph8 ----
    __builtin_amdgcn_sched_barrier(0);
    if (more) { SGA(1, td, 128); SGA(1, td, 192); SGB(1, td, 0); }
    BAR_();
    PRIO_ON_();
#pragma unroll
    for (int mi = 2; mi < 4; ++mi)
#pragma unroll
      for (int ni = 0; ni < 2; ++ni) {
        MFMA_(acc[mi][2 + ni], a[mi][0], bh[ni][0]);
        MFMA_(acc[mi][2 + ni], a[mi][1], bh[ni][1]);
      }
    PRIO_OFF_();
    if (more) { asm volatile("s_waitcnt vmcnt(5)" ::: "memory"); }
    else      { asm volatile("s_waitcnt vmcnt(0)" ::: "memory"); }
    __builtin_amdgcn_s_barrier();
    __builtin_amdgcn_sched_barrier(0);
  }

  float* Cz = Cp + (long)blockIdx.z * M * N;
#pragma unroll
  for (int mi = 0; mi < 4; ++mi)
#pragma unroll
    for (int ni = 0; ni < 4; ++ni)
#pragma unroll
      for (int r = 0; r < 4; ++r) {
        int row = m0 + wm + mi * 16 + quad * 4 + r;
        int col = n0 + wn + ni * 16 + l16;
        Cz[(long)row * N + col] = acc[mi][ni][r];
      }
#undef SGA
#undef SGB
#undef RDA
#undef RDB
}

// ---------------- sum two split-K partials ----------------
__global__ void add2(const float* __restrict__ p0, const float* __restrict__ p1,
                     float* __restrict__ out, int n4) {
  int i = blockIdx.x * 256 + threadIdx.x;
  if (i < n4) {
    float4 a = ((const float4*)p0)[i];
    float4 b = ((const float4*)p1)[i];
    float4 o;
    o.x = a.x + b.x; o.y = a.y + b.y; o.z = a.z + b.z; o.w = a.w + b.w;
    ((float4*)out)[i] = o;
  }
}

// ---------------- beta / g projections + fused hidden bf16 cast --------------
__global__ __launch_bounds__(256) void small_proj(const float* __restrict__ hidden,
                                                  const float* __restrict__ Wba32,
                                                  const float* __restrict__ dt_bias,
                                                  const float* __restrict__ A_log,
                                                  float* __restrict__ betaT,
                                                  float* __restrict__ gT,
                                                  short* __restrict__ hbf) {
  __shared__ float red[2][32][33];
  int r0 = blockIdx.x * 2;
  int tid = threadIdx.x;
  int cg = tid & 7, s = tid >> 3;
  const f32x4* wp = (const f32x4*)Wba32 + (long)s * 64 * 8 + cg;
  const f32x4* h0 = (const f32x4*)(hidden + (long)r0 * D_ + s * 64);
  const f32x4* h1 = (const f32x4*)(hidden + (long)(r0 + 1) * D_ + s * 64);
  f32x4 a0 = {0.f, 0.f, 0.f, 0.f}, a1 = {0.f, 0.f, 0.f, 0.f};
#pragma unroll
  for (int ii = 0; ii < 16; ++ii) {
    f32x4 ha = h0[ii], hb = h1[ii];
    f32x4 w0 = wp[(ii * 4 + 0) * 8];
    f32x4 w1 = wp[(ii * 4 + 1) * 8];
    f32x4 w2 = wp[(ii * 4 + 2) * 8];
    f32x4 w3 = wp[(ii * 4 + 3) * 8];
    a0 += ha[0] * w0; a1 += hb[0] * w0;
    a0 += ha[1] * w1; a1 += hb[1] * w1;
    a0 += ha[2] * w2; a1 += hb[2] * w2;
    a0 += ha[3] * w3; a1 += hb[3] * w3;
  }
#pragma unroll
  for (int j = 0; j < 4; ++j) {
    red[0][s][cg * 4 + j] = a0[j];
    red[1][s][cg * 4 + j] = a1[j];
  }
  // fused bf16 cast of hidden rows r0, r0+1 (L1-hot re-reads, coalesced 16B/lane)
  {
    int colb = s * 64 + cg * 8;
    const float* p0 = hidden + (long)r0 * D_ + colb;
    const float* p1 = p0 + D_;
    float4 x0 = *(const float4*)(p0);
    float4 x1 = *(const float4*)(p0 + 4);
    float4 y0 = *(const float4*)(p1);
    float4 y1 = *(const float4*)(p1 + 4);
    short8 o0, o1;
    o0[0] = f2bf(x0.x); o0[1] = f2bf(x0.y); o0[2] = f2bf(x0.z); o0[3] = f2bf(x0.w);
    o0[4] = f2bf(x1.x); o0[5] = f2bf(x1.y); o0[6] = f2bf(x1.z); o0[7] = f2bf(x1.w);
    o1[0] = f2bf(y0.x); o1[1] = f2bf(y0.y); o1[2] = f2bf(y0.z); o1[3] = f2bf(y0.w);
    o1[4] = f2bf(y1.x); o1[5] = f2bf(y1.y); o1[6] = f2bf(y1.z); o1[7] = f2bf(y1.w);
    *(short8*)(hbf + (long)r0 * D_ + colb) = o0;
    *(short8*)(hbf + (long)(r0 + 1) * D_ + colb) = o1;
  }
  __syncthreads();
  if (tid < 64) {
    int row = tid >> 5, c = tid & 31;
    float t0 = 0.f, t1 = 0.f, t2 = 0.f, t3 = 0.f;
#pragma unroll
    for (int ss = 0; ss < 32; ss += 4) {
      t0 += red[row][ss][c];
      t1 += red[row][ss + 1][c];
      t2 += red[row][ss + 2][c];
      t3 += red[row][ss + 3][c];
    }
    float t = (t0 + t1) + (t2 + t3);
    int r = r0 + row;
    if (c < 16) {
      betaT[c * BT_ + r] = 1.f / (1.f + __expf(-t));
    } else {
      int hh = c - 16;
      float y = t + dt_bias[hh];
      float sp = fmaxf(y, 0.f) + log1pf(__expf(-fabsf(y)));
      gT[hh * BT_ + r] = -__expf(A_log[hh]) * sp;   // raw g (log decay)
    }
  }
}

// ---------------- fused depthwise causal conv + SiLU + q/k l2norm ------------
// grid = BT * 32 groups of 128 channels, 64 threads (2 ch/thread).
// groups 0..15 = q|k heads -> l2norm + scale + bf16 out (never hit HBM as f32).
// groups 16..31 = v -> f32 to qkv's v region.
__global__ __launch_bounds__(64) void conv_qk(const float* __restrict__ mixed,
                                              const float* __restrict__ w,
                                              float* __restrict__ qkv,
                                              short* __restrict__ qb,
                                              short* __restrict__ kb) {
  int bi = blockIdx.x;
  int g = bi & 31, bt = bi >> 5;
  int t = bt & (T_ - 1);
  int lane = threadIdx.x;
  int c = g * 128 + lane * 2;
  const float* xp = mixed + (long)bt * CONV_DIM_ + c;
  float4 w0 = *(const float4*)(w + c * 4);
  float4 w1 = *(const float4*)(w + c * 4 + 4);
  float2 x0 = *(const float2*)(xp);
  float y0 = w0.w * x0.x, y1 = w1.w * x0.y;
  if (t >= 1) { float2 xm = *(const float2*)(xp - CONV_DIM_);     y0 += w0.z * xm.x; y1 += w1.z * xm.y; }
  if (t >= 2) { float2 xm = *(const float2*)(xp - 2 * CONV_DIM_); y0 += w0.y * xm.x; y1 += w1.y * xm.y; }
  if (t >= 3) { float2 xm = *(const float2*)(xp - 3 * CONV_DIM_); y0 += w0.x * xm.x; y1 += w1.x * xm.y; }
  y0 = y0 * (1.f / (1.f + __expf(-y0)));
  y1 = y1 * (1.f / (1.f + __expf(-y1)));
  if (g >= 16) {
    float2 o; o.x = y0; o.y = y1;
    *(float2*)(qkv + (long)bt * CONV_DIM_ + c) = o;
  } else {
    float ss = y0 * y0 + y1 * y1;
#pragma unroll
    for (int m = 32; m; m >>= 1) ss += __shfl_xor(ss, m, 64);
    float scale = rsqrtf(ss + 1e-6f);
    int which = g >> 3, h = g & 7;
    if (which == 0) scale *= 0.08838834764831845f;  // DK^-0.5 (q)
    short* dst = (which ? kb : qb) + ((long)bt * HK_ + h) * DK_;
    short2 o; o.x = f2bf(y0 * scale); o.y = f2bf(y1 * scale);
    ((short2*)dst)[lane] = o;
  }
}

// ================= PHASE 1: per-chunk local quantities (parallel, 512 blocks)
__global__ __launch_bounds__(256, 2) void chunk_phase1(
    const short* __restrict__ qbf, const short* __restrict__ kbf,
    const float* __restrict__ qkv, const float* __restrict__ gT,
    const float* __restrict__ bT,
    short* __restrict__ Pm, short* __restrict__ GQ, short* __restrict__ KtT,
    short* __restrict__ Wneg, float* __restrict__ Ut, float* __restrict__ Gammac) {
  __shared__ float Al[64 * 64];      // 16 KB
  __shared__ float Gs[64], Gam[64], Dd[64], Bet[64], BG[64];

  int ci = blockIdx.x;
  int c = ci & 15, hv = (ci >> 4) & 15, b = ci >> 8;
  int hk = hv >> 1;
  int t0 = c * CL_;
  int tid = threadIdx.x;
  int wave = tid >> 6, lane = tid & 63, quad = lane >> 4, l16 = lane & 15;

  if (tid < 64) {
    float g = gT[(hv * B_ + b) * T_ + t0 + tid];
    float x = g;
#pragma unroll
    for (int off = 1; off < 64; off <<= 1) {
      float y = __shfl_up(x, off, 64);
      if (tid >= off) x += y;
    }
    Gs[tid] = x;
    float gm = __expf(x);
    Gam[tid] = gm;
    float Gtot = __shfl(x, 63, 64);
    Dd[tid] = __expf(Gtot - x);
    float bb = bT[(hv * B_ + b) * T_ + t0 + tid];
    Bet[tid] = bb;
    BG[tid] = bb * gm;
    if (tid == 63) Gammac[ci] = __expf(x);
  }
  __syncthreads();

  const long kbase = ((long)(b * T_ + t0) * HK_ + hk) * DK_;   // in shorts
  const int kstride = HK_ * DK_;                               // 1024

  int half = tid >> 7;        // 0 = V-columns, 1 = betaGammaK-columns
  int col = tid & 127;

  // ---- KK^T -> Al (mask s>r, scale beta_s * exp(G_s - G_r)) ----
  {
    f32x4 acc[4] = {};
#pragma unroll
    for (int kk = 0; kk < 4; ++kk) {
      short8 afr = *(const short8*)(kbf + kbase + (long)(16 * wave + l16) * kstride + kk * 32 + quad * 8);
#pragma unroll
      for (int j = 0; j < 4; ++j) {
        short8 bfr = *(const short8*)(kbf + kbase + (long)(16 * j + l16) * kstride + kk * 32 + quad * 8);
        acc[j] = __builtin_amdgcn_mfma_f32_16x16x32_bf16(afr, bfr, acc[j], 0, 0, 0);
      }
    }
#pragma unroll
    for (int j = 0; j < 4; ++j)
#pragma unroll
      for (int r = 0; r < 4; ++r) {
        int row = 16 * wave + quad * 4 + r, colx = 16 * j + l16;
        float v = 0.f;
        if (row > colx) v = Bet[row] * __expf(Gs[row] - Gs[colx]) * acc[j][r];
        Al[row * 64 + colx] = v;
      }
  }
  // ---- QK^T -> Pm (mask t>=s, scale exp(G_t - G_s)) ----
  {
    f32x4 acc[4] = {};
#pragma unroll
    for (int kk = 0; kk < 4; ++kk) {
      short8 afr = *(const short8*)(qbf + kbase + (long)(16 * wave + l16) * kstride + kk * 32 + quad * 8);
#pragma unroll
      for (int j = 0; j < 4; ++j) {
        short8 bfr = *(const short8*)(kbf + kbase + (long)(16 * j + l16) * kstride + kk * 32 + quad * 8);
        acc[j] = __builtin_amdgcn_mfma_f32_16x16x32_bf16(afr, bfr, acc[j], 0, 0, 0);
      }
    }
#pragma unroll
    for (int j = 0; j < 4; ++j)
#pragma unroll
      for (int r = 0; r < 4; ++r) {
        int row = 16 * wave + quad * 4 + r, colx = 16 * j + l16;
        float v = 0.f;
        if (row >= colx) v = __expf(Gs[row] - Gs[colx]) * acc[j][r];
        Pm[(long)ci * 4096 + row * 64 + colx] = f2bf(v);
      }
  }
  // ---- GQ[s][d] = Gam[s]*q[s][d] (coalesced short2 writes) ----
  for (int s = wave; s < 64; s += 4) {
    float gm = Gam[s];
    short2 qv = *(const short2*)(qbf + kbase + (long)s * kstride + lane * 2);
    short2 o;
    o.x = f2bf(bf2f(qv.x) * gm);
    o.y = f2bf(bf2f(qv.y) * gm);
    *(short2*)(GQ + (long)ci * 8192 + s * 128 + lane * 2) = o;
  }
  // ---- KtT[d][s] = k[s][d]*Dd[s] ----
  for (int d = wave; d < 128; d += 4) {
    float kv = bf2f(kbf[kbase + (long)lane * kstride + d]);
    KtT[(long)ci * 8192 + d * 64 + lane] = f2bf(kv * Dd[lane]);
  }

  // ---- RHS columns into registers (issued here: latency hides under the
  //      barrier; u[64] not live during the MFMA sections above) ----
  float u[64];
  {
    const float* vcol = qkv + (long)(b * T_ + t0) * CONV_DIM_ + 2 * KEY_DIM_ + hv * DV_ + col;
    const short* kcol = kbf + kbase + col;
    if (half == 0) {
#pragma unroll
      for (int r = 0; r < 64; ++r) u[r] = vcol[(long)r * CONV_DIM_];
    } else {
#pragma unroll
      for (int r = 0; r < 64; ++r) u[r] = bf2f(kcol[(long)r * kstride]);
    }
  }
  __syncthreads();   // Al complete

  // ---- scale RHS ----
  if (half == 0) {
#pragma unroll
    for (int r = 0; r < 64; ++r) u[r] *= Bet[r];
  } else {
#pragma unroll
    for (int r = 0; r < 64; ++r) u[r] *= BG[r];
  }

  // ---- right-looking blocked forward substitution ----
#pragma unroll
  for (int rb = 0; rb < 64; rb += 4) {
    {
      const float* A1 = Al + (rb + 1) * 64 + rb;
      const float* A2 = Al + (rb + 2) * 64 + rb;
      const float* A3 = Al + (rb + 3) * 64 + rb;
      u[rb + 1] -= A1[0] * u[rb];
      u[rb + 2] -= A2[0] * u[rb] + A2[1] * u[rb + 1];
      u[rb + 3] -= A3[0] * u[rb] + A3[1] * u[rb + 1] + A3[2] * u[rb + 2];
    }
    float u0 = u[rb], u1 = u[rb + 1], u2 = u[rb + 2], u3 = u[rb + 3];
#pragma unroll
    for (int s = rb + 4; s < 64; ++s) {
      float4 a4 = *(const float4*)(Al + s * 64 + rb);
      u[s] -= (a4.x * u0 + a4.y * u1) + (a4.z * u2 + a4.w * u3);
    }
  }

  // ---- write out (coalesced) ----
  if (half == 0) {
    float* up = Ut + (long)ci * 8192 + col;
#pragma unroll
    for (int s = 0; s < 64; ++s) up[s * 128] = u[s];
  } else {
    short* wp = Wneg + (long)ci * 8192 + col;
#pragma unroll
    for (int s = 0; s < 64; ++s) wp[s * 128] = f2bf(-u[s]);
  }
}

// ================= PHASE 2: state recurrence over chunks (256 blocks) ========
__global__ __launch_bounds__(256) void chunk_phase2(
    const short* __restrict__ Wneg, const float* __restrict__ Ut,
    const short* __restrict__ KtT, const float* __restrict__ Gammac,
    short* __restrict__ UTg, short* __restrict__ ScTg) {
  __shared__ short SLT[16 * 136];   // S^T slice [n 16][m 128 pad 136]
  __shared__ short ULT[16 * 72];    // U'^T slice [n 16][s 64 pad 72]
  int bi = blockIdx.x >> 3;          // b*16+hv
  int n0 = (blockIdx.x & 7) * 16;    // col-slice base
  int tid = threadIdx.x, wave = tid >> 6, lane = tid & 63, quad = lane >> 4, l16 = lane & 15;
  f32x4 S2[2] = {};   // rows 32*wave+16i+quad*4+r, col n0+l16

  long ci0 = (long)bi * NCH_;
  // preload chunk-0 operands
  short8 Wr[4]; f32x4 Ur; short8 Kr[2][2];
  {
    long ci = ci0;
#pragma unroll
    for (int kk = 0; kk < 4; ++kk)
      Wr[kk] = *(const short8*)(Wneg + ci * 8192 + (16 * wave + l16) * 128 + kk * 32 + quad * 8);
    const float* up = Ut + ci * 8192 + (16 * wave + quad * 4) * 128 + n0 + l16;
#pragma unroll
    for (int r = 0; r < 4; ++r) Ur[r] = up[r * 128];
#pragma unroll
    for (int kk = 0; kk < 2; ++kk)
#pragma unroll
      for (int i = 0; i < 2; ++i)
        Kr[kk][i] = *(const short8*)(KtT + ci * 8192 + (32 * wave + 16 * i + l16) * 64 + kk * 32 + quad * 8);
  }

  for (int ch = 0; ch < NCH_; ++ch) {
    long ci = ci0 + ch;
    // 1. write S^T slice to LDS + global
#pragma unroll
    for (int i = 0; i < 2; ++i) {
      int m0 = 32 * wave + 16 * i + quad * 4;
      short4 p;
      p.x = f2bf(S2[i][0]); p.y = f2bf(S2[i][1]);
      p.z = f2bf(S2[i][2]); p.w = f2bf(S2[i][3]);
      *(short4*)(SLT + l16 * 136 + m0) = p;
      *(short4*)(ScTg + ci * 16384 + (n0 + l16) * 128 + m0) = p;
    }
    // prefetch next-chunk operands into registers (overlaps barriers + MFMA)
    short8 Wn[4]; f32x4 Un; short8 Kn[2][2];
    if (ch + 1 < NCH_) {
      long cj = ci + 1;
#pragma unroll
      for (int kk = 0; kk < 4; ++kk)
        Wn[kk] = *(const short8*)(Wneg + cj * 8192 + (16 * wave + l16) * 128 + kk * 32 + quad * 8);
      const float* up = Ut + cj * 8192 + (16 * wave + quad * 4) * 128 + n0 + l16;
#pragma unroll
      for (int r = 0; r < 4; ++r) Un[r] = up[r * 128];
#pragma unroll
      for (int kk = 0; kk < 2; ++kk)
#pragma unroll
        for (int i = 0; i < 2; ++i)
          Kn[kk][i] = *(const short8*)(KtT + cj * 8192 + (32 * wave + 16 * i + l16) * 64 + kk * 32 + quad * 8);
    }
    __syncthreads();
    // 2. U' = U - W @ S^T  (contraction over m=128)
    f32x4 Ua = Ur;
#pragma unroll
    for (int kk = 0; kk < 4; ++kk) {
      short8 bfv = *(const short8*)(SLT + l16 * 136 + kk * 32 + quad * 8);
      Ua = __builtin_amdgcn_mfma_f32_16x16x32_bf16(Wr[kk], bfv, Ua, 0, 0, 0);
    }
    {
      int s0 = 16 * wave + quad * 4;
      short4 p;
      p.x = f2bf(Ua[0]); p.y = f2bf(Ua[1]); p.z = f2bf(Ua[2]); p.w = f2bf(Ua[3]);
      *(short4*)(ULT + l16 * 72 + s0) = p;
      *(short4*)(UTg + ci * 8192 + (n0 + l16) * 64 + s0) = p;
    }
    __syncthreads();
    // 3. S = S*gamma + KtT @ U'^T  (contraction over s=64)
    float gc = Gammac[ci];
#pragma unroll
    for (int i = 0; i < 2; ++i)
#pragma unroll
      for (int r = 0; r < 4; ++r) S2[i][r] *= gc;
#pragma unroll
    for (int kk = 0; kk < 2; ++kk) {
      short8 bfv = *(const short8*)(ULT + l16 * 72 + kk * 32 + quad * 8);
#pragma unroll
      for (int i = 0; i < 2; ++i)
        S2[i] = __builtin_amdgcn_mfma_f32_16x16x32_bf16(Kr[kk][i], bfv, S2[i], 0, 0, 0);
    }
    __syncthreads();
    if (ch + 1 < NCH_) {
#pragma unroll
      for (int kk = 0; kk < 4; ++kk) Wr[kk] = Wn[kk];
      Ur = Un;
#pragma unroll
      for (int kk = 0; kk < 2; ++kk)
#pragma unroll
        for (int i = 0; i < 2; ++i) Kr[kk][i] = Kn[kk][i];
    }
  }
}

// ================= PHASE 3: outputs + fused gated RMSNorm (512 blocks) =======
__global__ __launch_bounds__(256) void chunk_phase3(
    const short* __restrict__ GQ, const short* __restrict__ ScTg,
    const short* __restrict__ Pm, const short* __restrict__ UTg,
    const float* __restrict__ zbuf, const float* __restrict__ nw,
    short* __restrict__ obf) {
  int ci = blockIdx.x;
  int c = ci & 15, hv = (ci >> 4) & 15, b = ci >> 8;
  int t0 = c * CL_;
  int tid = threadIdx.x, wave = tid >> 6, lane = tid & 63, quad = lane >> 4, l16 = lane & 15;
  f32x4 acc[8] = {};
#pragma unroll
  for (int kk = 0; kk < 4; ++kk) {
    short8 af = *(const short8*)(GQ + (long)ci * 8192 + (16 * wave + l16) * 128 + kk * 32 + quad * 8);
#pragma unroll
    for (int j = 0; j < 8; ++j) {
      short8 bfv = *(const short8*)(ScTg + (long)ci * 16384 + (16 * j + l16) * 128 + kk * 32 + quad * 8);
      acc[j] = __builtin_amdgcn_mfma_f32_16x16x32_bf16(af, bfv, acc[j], 0, 0, 0);
    }
  }
#pragma unroll
  for (int kk = 0; kk < 2; ++kk) {
    short8 af = *(const short8*)(Pm + (long)ci * 4096 + (16 * wave + l16) * 64 + kk * 32 + quad * 8);
#pragma unroll
    for (int j = 0; j < 8; ++j) {
      short8 bfv = *(const short8*)(UTg + (long)ci * 8192 + (16 * j + l16) * 64 + kk * 32 + quad * 8);
      acc[j] = __builtin_amdgcn_mfma_f32_16x16x32_bf16(af, bfv, acc[j], 0, 0, 0);
    }
  }
  // fused gated RMSNorm * silu(z) epilogue.
#pragma unroll
  for (int r = 0; r < 4; ++r) {
    float ss = 0.f;
#pragma unroll
    for (int j = 0; j < 8; ++j) ss += acc[j][r] * acc[j][r];
    ss += __shfl_xor(ss, 1, 64);
    ss += __shfl_xor(ss, 2, 64);
    ss += __shfl_xor(ss, 4, 64);
    ss += __shfl_xor(ss, 8, 64);
    float scale = rsqrtf(ss * (1.f / 128.f) + 1e-6f);
    int t = t0 + 16 * wave + quad * 4 + r;
    long base = (long)(b * T_ + t) * VALUE_DIM_ + hv * DV_;
#pragma unroll
    for (int j = 0; j < 8; ++j) {
      int n = 16 * j + l16;
      float zv = zbuf[base + n];
      float sz = zv * (1.f / (1.f + __expf(-zv)));
      obf[base + n] = f2bf(acc[j][r] * scale * nw[n] * sz);
    }
  }
}

// ---------------- launcher ----------------
extern "C" void kernel_launch(void* const* d_in, const int* in_sizes, int n_in,
                              void* d_out, int out_size, void* d_ws, size_t ws_size,
                              hipStream_t stream) {
  const float* hidden  = (const float*)d_in[0];
  const float* W_qkv   = (const float*)d_in[1];
  const float* W_z     = (const float*)d_in[2];
  const float* W_b     = (const float*)d_in[3];
  const float* W_a     = (const float*)d_in[4];
  const float* conv_w  = (const float*)d_in[5];
  const float* dt_bias = (const float*)d_in[6];
  const float* A_log   = (const float*)d_in[7];
  const float* norm_w  = (const float*)d_in[8];
  const float* W_out   = (const float*)d_in[9];
  float* out = (float*)d_out;

  char* ws = (char*)d_ws;
  size_t off = 0;
  auto alloc = [&](size_t bytes) {
    void* p = ws + off;
    off += (bytes + 255) & ~(size_t)255;
    return p;
  };
  short* hidden_bf = (short*)alloc((size_t)BT_ * D_ * 2);           // 8 MB
  short* WcatT     = (short*)alloc((size_t)(CONV_DIM_ + VALUE_DIM_) * D_ * 2); // 24 MB
  short* WoutT     = (short*)alloc((size_t)D_ * VALUE_DIM_ * 2);    // 8 MB
  float* mixed     = (float*)alloc((size_t)BT_ * CONV_DIM_ * 4);    // 32 MB
  float* qkv       = (float*)alloc((size_t)BT_ * CONV_DIM_ * 4);    // 32 MB
  float* zbuf      = (float*)alloc((size_t)BT_ * VALUE_DIM_ * 4);   // 16 MB
  short* qbf       = (short*)alloc((size_t)BT_ * KEY_DIM_ * 2);     // 4 MB
  short* kbf       = (short*)alloc((size_t)BT_ * KEY_DIM_ * 2);     // 4 MB
  float* betab     = (float*)alloc((size_t)BT_ * HV_ * 4);
  float* gb        = (float*)alloc((size_t)BT_ * HV_ * 4);
  float* Wba32     = (float*)alloc((size_t)D_ * 32 * 4);            // 256 KB
  short* Wneg      = (short*)alloc((size_t)512 * 8192 * 2);         // 8 MB
  float* Ut32      = (float*)alloc((size_t)512 * 8192 * 4);         // 16 MB
  short* KtT       = (short*)alloc((size_t)512 * 8192 * 2);         // 8 MB
  short* UTg       = (short*)alloc((size_t)512 * 8192 * 2);         // 8 MB
  short* ScTg      = (short*)alloc((size_t)512 * 16384 * 2);        // 16 MB
  float* Gammac    = (float*)alloc((size_t)512 * 4);
  // aliases (into buffers dead by the time they're written):
  short* Pm   = (short*)(mixed + (size_t)BT_ * VALUE_DIM_);         // 4 MB (mixed dead after conv)
  short* GQ   = Pm + (size_t)512 * 4096;                            // 8 MB
  short* obf  = hidden_bf;          // dead after fused qkv+z GEMM
  float* Cpart = qkv;               // 32 MB; qkv dead after phase1 (split-K partials)

  // merged weight prep: 3 transposes + W_b|W_a interleave in ONE launch
  prep_weights<<<dim3(128, 64, 4), dim3(32, 8), 0, stream>>>(
      W_qkv, W_z, W_out, W_b, W_a, WcatT, WoutT, Wba32);

  // beta/g projections + fused hidden bf16 cast (must precede the GEMM)
  small_proj<<<BT_ / 2, 256, 0, stream>>>(hidden, Wba32, dt_bias, A_log, betab, gb, hidden_bf);

  // fused qkv + z projection: 256x192 8-phase, grid 32x8 = 256 blocks (1/CU)
  gemm256n192<<<dim3((CONV_DIM_ + VALUE_DIM_) / 192, BT_ / 256), 512, 0, stream>>>(
      hidden_bf, WcatT, mixed, zbuf, CONV_DIM_, VALUE_DIM_, D_);

  // fused conv+SiLU+qknorm: q/k go straight to bf16, v to qkv's v region
  conv_qk<<<BT_ * 32, 64, 0, stream>>>(mixed, conv_w, qkv, qbf, kbf);

  chunk_phase1<<<512, 256, 0, stream>>>(qbf, kbf, qkv, gb, betab, Pm, GQ, KtT, Wneg, Ut32, Gammac);
  chunk_phase2<<<256, 256, 0, stream>>>(Wneg, Ut32, KtT, Gammac, UTg, ScTg);
  chunk_phase3<<<512, 256, 0, stream>>>(GQ, ScTg, Pm, UTg, zbuf, norm_w, obf);

  // out projection: 256x128 8-phase split-K=2 -> 256 blocks, then partial-sum
  gemm256ks<<<dim3(D_ / 128, BT_ / 256, 2), 512, 0, stream>>>(obf, WoutT, Cpart, BT_, D_, VALUE_DIM_);
  add2<<<(BT_ * D_ / 4 + 255) / 256, 256, 0, stream>>>(Cpart, Cpart + (size_t)BT_ * D_, out, BT_ * D_ / 4);
}